// Round 8
// baseline (1406.300 us; speedup 1.0000x reference)
//
#include <hip/hip_runtime.h>
#include <cstdint>
#include <cstddef>

#define HID 128
#define INC 256
#define NLAYER 3
#define NB_KVS 768
#define SLOTS 96
#define NBIN 8

static constexpr float EPS = 1e-5f;

typedef __attribute__((ext_vector_type(8))) short s16x8;
typedef __attribute__((ext_vector_type(4))) unsigned short us16x4;
typedef __attribute__((ext_vector_type(4))) float f32x4;
typedef __attribute__((ext_vector_type(2))) float f32x2;

__device__ __forceinline__ float eluf(float x) { return x > 0.f ? x : expm1f(x); }

__device__ __forceinline__ unsigned short f2bf(float x)
{
    unsigned u = __float_as_uint(x);
    u += 0x7FFFu + ((u >> 16) & 1u);
    return (unsigned short)(u >> 16);
}

__device__ __forceinline__ float bf2f(unsigned short u)
{
    return __uint_as_float(((unsigned)u) << 16);
}

__device__ __forceinline__ void bf16split(float a, unsigned short& h, unsigned short& l)
{
    h = f2bf(a);
    float hf = __uint_as_float(((unsigned)h) << 16);
    l = f2bf(a - hf);
}

__device__ __forceinline__ unsigned char f2fp8(float x)
{
    return (unsigned char)(__builtin_amdgcn_cvt_pk_fp8_f32(x, x, 0, false) & 0xFF);
}

// ---------------------------------------------------------------------------
// MLP GEMM: C = ELU(BN(A[n,K] @ W + bias)), split-bf16 3-term.
// OUT16: write bf16 (final MLP layer -> h16), else f32.
// ---------------------------------------------------------------------------
template<int K, bool OUT16>
__global__ __launch_bounds__(256) void gemm_mlp(
    const float* __restrict__ A,
    const unsigned short* __restrict__ Wth, const unsigned short* __restrict__ Wtl,
    const float* __restrict__ bias,
    const float* __restrict__ bng, const float* __restrict__ bnb,
    const float* __restrict__ bnm, const float* __restrict__ bnv,
    float* __restrict__ C, unsigned short* __restrict__ C16, int n)
{
    __shared__ unsigned short Ah[64 * 64], Al[64 * 64], Wh[128 * 64], Wl[128 * 64];
    const int t = threadIdx.x;
    const int l = t & 63;
    const int w = t >> 6;
    const int l15 = l & 15;
    const int row0 = blockIdx.x * 64;

    char* cAh = (char*)Ah; char* cAl = (char*)Al;
    char* cWh = (char*)Wh; char* cWl = (char*)Wl;

    f32x4 acc[8] = {};

    for (int kc = 0; kc < K; kc += 64) {
        #pragma unroll
        for (int i = 0; i < 4; ++i) {
            int f = t + 256 * i;
            int r = f >> 4, c4 = f & 15;
            int gr = row0 + r; if (gr > n - 1) gr = n - 1;
            float4 a4 = *(const float4*)&A[(size_t)gr * K + kc + c4 * 4];
            unsigned short h0, h1, h2, h3, l0, l1, l2, l3;
            bf16split(a4.x, h0, l0); bf16split(a4.y, h1, l1);
            bf16split(a4.z, h2, l2); bf16split(a4.w, h3, l3);
            int byte = r * 128 + (((c4 >> 1) * 16) ^ ((r & 7) << 4)) + (c4 & 1) * 8;
            *(us16x4*)(cAh + byte) = (us16x4){h0, h1, h2, h3};
            *(us16x4*)(cAl + byte) = (us16x4){l0, l1, l2, l3};
        }
        #pragma unroll
        for (int i = 0; i < 4; ++i) {
            int f = t + 256 * i;
            int nr = f >> 3, c8 = f & 7;
            size_t gsrc = (size_t)nr * K + kc + c8 * 8;
            int byte = nr * 128 + ((c8 * 16) ^ ((nr & 7) << 4));
            *(s16x8*)(cWh + byte) = *(const s16x8*)&Wth[gsrc];
            *(s16x8*)(cWl + byte) = *(const s16x8*)&Wtl[gsrc];
        }
        __syncthreads();
        #pragma unroll
        for (int ks = 0; ks < 2; ++ks) {
            int jA = ks * 4 + (l >> 4);
            int ar = w * 16 + l15;
            int aoff = ar * 128 + ((jA * 16) ^ ((ar & 7) << 4));
            s16x8 fah = *(s16x8*)(cAh + aoff);
            s16x8 fal = *(s16x8*)(cAl + aoff);
            #pragma unroll
            for (int nt = 0; nt < 8; ++nt) {
                int nr = nt * 16 + l15;
                int boff = nr * 128 + ((jA * 16) ^ ((nr & 7) << 4));
                s16x8 fbh = *(s16x8*)(cWh + boff);
                s16x8 fbl = *(s16x8*)(cWl + boff);
                acc[nt] = __builtin_amdgcn_mfma_f32_16x16x32_bf16(fah, fbh, acc[nt], 0, 0, 0);
                acc[nt] = __builtin_amdgcn_mfma_f32_16x16x32_bf16(fah, fbl, acc[nt], 0, 0, 0);
                acc[nt] = __builtin_amdgcn_mfma_f32_16x16x32_bf16(fal, fbh, acc[nt], 0, 0, 0);
            }
        }
        __syncthreads();
    }

    const int rbase = row0 + w * 16 + ((l >> 4) << 2);
    #pragma unroll
    for (int nt = 0; nt < 8; ++nt) {
        int col = nt * 16 + l15;
        float bb = bias[col];
        float gm = bng[col], bt = bnb[col], mn = bnm[col], vr = bnv[col];
        #pragma unroll
        for (int r = 0; r < 4; ++r) {
            int row = rbase + r;
            if (row < n) {
                float o = acc[nt][r] + bb;
                o = eluf((o - mn) * rsqrtf(vr + EPS) * gm + bt);
                if (OUT16) C16[(size_t)row * HID + col] = f2bf(o);
                else       C  [(size_t)row * HID + col] = o;
            }
        }
    }
}

// ---------------------------------------------------------------------------
// Fused per-layer QKVGR, hi-only bf16, double-buffered W staging.
// A = h (bf16). LDS: [A 16KB][W buf0 32KB][W buf1 32KB] = 80KB, 2 blocks/CU.
//   m=0 q: +bias, L2-norm -> qb(bf16)    m=1 k: +bias, L2-norm -> kb(bf16)
//   m=2 v: +bias -> vb(bf16)             m=3 g: +bias -> gb (fp8 e4m3)
//   m=4 r: +bias + h(res, bf16) -> acc (f32)
// ---------------------------------------------------------------------------
struct QKVGRArgs {
    const unsigned short* wh[5];
    const float* bias[5];
};

__global__ __launch_bounds__(256) void fused_qkvgr(
    const unsigned short* __restrict__ A16, QKVGRArgs ar,
    unsigned short* __restrict__ qb16, unsigned short* __restrict__ kb16,
    unsigned short* __restrict__ vb16,
    unsigned char* __restrict__ gb8, float* __restrict__ accout, int n)
{
    __shared__ char smem[81920];
    char* cA = smem;                                      // 16KB
    char* wb0 = smem + 16384;                             // 32KB
    char* wb1 = smem + 49152;                             // 32KB

    const int t = threadIdx.x;
    const int l = t & 63;
    const int w = t >> 6;
    const int l15 = l & 15;
    const int row0 = blockIdx.x * 64;

    // ---- stage A (bf16 copy, swizzled, row stride 256B) ----
    #pragma unroll
    for (int i = 0; i < 4; ++i) {
        int f = t + 256 * i;
        int r = f >> 4, c8 = f & 15;
        int gr = row0 + r; if (gr > n - 1) gr = n - 1;
        int byte = r * 256 + ((c8 * 16) ^ ((r & 7) << 4));
        *(s16x8*)(cA + byte) = *(const s16x8*)&A16[(size_t)gr * HID + c8 * 8];
    }
    __syncthreads();

    s16x8 fah[4];
    {
        const int arow = w * 16 + l15;
        #pragma unroll
        for (int ks = 0; ks < 4; ++ks) {
            int aoff = arow * 256 + (((ks * 64) + (l >> 4) * 16) ^ ((arow & 7) << 4));
            fah[ks] = *(s16x8*)(cA + aoff);
        }
    }
    // stage W0 -> wb0 (disjoint from cA; frag loads are thread-local)
    {
        const unsigned short* wh = ar.wh[0];
        #pragma unroll
        for (int i = 0; i < 8; ++i) {
            int f = t + 256 * i;
            int nr = f >> 4, c8 = f & 15;
            int byte = nr * 256 + ((c8 * 16) ^ ((nr & 7) << 4));
            *(s16x8*)(wb0 + byte) = *(const s16x8*)&wh[(size_t)nr * HID + c8 * 8];
        }
    }
    __syncthreads();

    const int rbase = row0 + w * 16 + ((l >> 4) << 2);

    for (int m = 0; m < 5; ++m) {
        char* cw = (m & 1) ? wb1 : wb0;
        if (m < 4) {
            char* nw = (m & 1) ? wb0 : wb1;     // == buffer computed in m-1; safe after barrier
            const unsigned short* wh = ar.wh[m + 1];
            #pragma unroll
            for (int i = 0; i < 8; ++i) {
                int f = t + 256 * i;
                int nr = f >> 4, c8 = f & 15;
                int byte = nr * 256 + ((c8 * 16) ^ ((nr & 7) << 4));
                *(s16x8*)(nw + byte) = *(const s16x8*)&wh[(size_t)nr * HID + c8 * 8];
            }
        }

        f32x4 acc[8] = {};
        #pragma unroll
        for (int ks = 0; ks < 4; ++ks) {
            #pragma unroll
            for (int nt = 0; nt < 8; ++nt) {
                int nr = nt * 16 + l15;
                int boff = nr * 256 + (((ks * 64) + (l >> 4) * 16) ^ ((nr & 7) << 4));
                acc[nt] = __builtin_amdgcn_mfma_f32_16x16x32_bf16(fah[ks], *(s16x8*)(cw + boff), acc[nt], 0, 0, 0);
            }
        }

        float bb[8];
        #pragma unroll
        for (int nt = 0; nt < 8; ++nt) bb[nt] = ar.bias[m][nt * 16 + l15];

        if (m <= 1) {                       // q / k: bias + row L2 normalize, bf16
            unsigned short* out = (m == 0) ? qb16 : kb16;
            #pragma unroll
            for (int r = 0; r < 4; ++r) {
                float ss = 0.f;
                #pragma unroll
                for (int nt = 0; nt < 8; ++nt) {
                    float o = acc[nt][r] + bb[nt];
                    ss += o * o;
                }
                ss += __shfl_xor(ss, 1); ss += __shfl_xor(ss, 2);
                ss += __shfl_xor(ss, 4); ss += __shfl_xor(ss, 8);
                float rn = rsqrtf(ss);
                int row = rbase + r;
                if (row < n) {
                    #pragma unroll
                    for (int nt = 0; nt < 8; ++nt)
                        out[(size_t)row * HID + nt * 16 + l15] = f2bf((acc[nt][r] + bb[nt]) * rn);
                }
            }
        } else if (m == 2) {                // v: bias, bf16 store
            #pragma unroll
            for (int r = 0; r < 4; ++r) {
                int row = rbase + r;
                if (row < n) {
                    #pragma unroll
                    for (int nt = 0; nt < 8; ++nt)
                        vb16[(size_t)row * HID + nt * 16 + l15] = f2bf(acc[nt][r] + bb[nt]);
                }
            }
        } else if (m == 3) {                // g: bias, fp8 e4m3 store
            #pragma unroll
            for (int r = 0; r < 4; ++r) {
                int row = rbase + r;
                if (row < n) {
                    #pragma unroll
                    for (int nt = 0; nt < 8; ++nt)
                        gb8[(size_t)row * HID + nt * 16 + l15] = f2fp8(acc[nt][r] + bb[nt]);
                }
            }
        } else {                            // r: bias + residual(h bf16)
            #pragma unroll
            for (int r = 0; r < 4; ++r) {
                int row = rbase + r;
                if (row < n) {
                    #pragma unroll
                    for (int nt = 0; nt < 8; ++nt) {
                        int col = nt * 16 + l15;
                        accout[(size_t)row * HID + col] =
                            acc[nt][r] + bb[nt] + bf2f(A16[(size_t)row * HID + col]);
                    }
                }
            }
        }
        __syncthreads();
    }
}

// ---------------------------------------------------------------------------
// num+combine: accio += (qn @ kvs + sum_v) / (qn . sum_kn + nf)
// ---------------------------------------------------------------------------
__global__ __launch_bounds__(256) void gemm_num_combine(
    const unsigned short* __restrict__ A16,
    const unsigned short* __restrict__ Bth,
    const float* __restrict__ sumv, const float* __restrict__ snk,
    float nf, float* __restrict__ accio, int n)
{
    __shared__ char smem[16384 + 32768];
    char* cA = smem;
    char* cW = smem + 16384;

    const int t = threadIdx.x;
    const int l = t & 63;
    const int w = t >> 6;
    const int l15 = l & 15;
    const int row0 = blockIdx.x * 64;

    #pragma unroll
    for (int i = 0; i < 4; ++i) {
        int f = t + 256 * i;
        int r = f >> 4, c8 = f & 15;
        int gr = row0 + r; if (gr > n - 1) gr = n - 1;
        int byte = r * 256 + ((c8 * 16) ^ ((r & 7) << 4));
        *(s16x8*)(cA + byte) = *(const s16x8*)&A16[(size_t)gr * HID + c8 * 8];
    }
    #pragma unroll
    for (int i = 0; i < 8; ++i) {
        int f = t + 256 * i;
        int nr = f >> 4, c8 = f & 15;
        int byte = nr * 256 + ((c8 * 16) ^ ((nr & 7) << 4));
        *(s16x8*)(cW + byte) = *(const s16x8*)&Bth[(size_t)nr * HID + c8 * 8];
    }
    __syncthreads();

    f32x4 acc[8] = {};
    const int arow = w * 16 + l15;
    #pragma unroll
    for (int ks = 0; ks < 4; ++ks) {
        int aoff = arow * 256 + (((ks * 64) + (l >> 4) * 16) ^ ((arow & 7) << 4));
        s16x8 fa = *(s16x8*)(cA + aoff);
        #pragma unroll
        for (int nt = 0; nt < 8; ++nt) {
            int nr = nt * 16 + l15;
            int boff = nr * 256 + (((ks * 64) + (l >> 4) * 16) ^ ((nr & 7) << 4));
            acc[nt] = __builtin_amdgcn_mfma_f32_16x16x32_bf16(fa, *(s16x8*)(cW + boff), acc[nt], 0, 0, 0);
        }
    }

    const int rbase = row0 + w * 16 + ((l >> 4) << 2);
    float bb[8], skn[8];
    #pragma unroll
    for (int nt = 0; nt < 8; ++nt) {
        bb[nt]  = sumv[nt * 16 + l15];
        skn[nt] = snk[nt * 16 + l15];
    }
    #pragma unroll
    for (int r = 0; r < 4; ++r) {
        int row = rbase + r;
        float p = 0.f;
        if (row < n) {
            #pragma unroll
            for (int nt = 0; nt < 8; ++nt)
                p += bf2f(A16[(size_t)row * HID + nt * 16 + l15]) * skn[nt];
        }
        p += __shfl_xor(p, 1); p += __shfl_xor(p, 2);
        p += __shfl_xor(p, 4); p += __shfl_xor(p, 8);
        float dinv = 1.f / (p + nf);
        if (row < n) {
            #pragma unroll
            for (int nt = 0; nt < 8; ++nt) {
                size_t idx = (size_t)row * HID + nt * 16 + l15;
                accio[idx] += (acc[nt][r] + bb[nt]) * dinv;
            }
        }
    }
}

// ------------------- weight pre-split (+transpose) kernel -------------------
struct WConvArgs {
    const float* src[18];
    unsigned short* dh[18];
    unsigned short* dl[18];
    int K[18];
};

__global__ void conv_weights(WConvArgs a)
{
    int m = blockIdx.x;
    const float* s = a.src[m];
    unsigned short* dh = a.dh[m];
    unsigned short* dl = a.dl[m];
    int K = a.K[m];
    int tot = 128 * K;
    int slice = (tot + gridDim.y - 1) / gridDim.y;
    int i0 = blockIdx.y * slice;
    int i1 = min(tot, i0 + slice);
    for (int idx = i0 + threadIdx.x; idx < i1; idx += 256) {
        int nn = idx / K, k = idx - nn * K;
        float v = s[(size_t)k * 128 + nn];
        bf16split(v, dh[idx], dl[idx]);
    }
}

// ---------------- kvs stage 1: per-block partial kn^T @ v (bf16 in) ---------
__global__ __launch_bounds__(256) void reduce_kvs_p1(
    const unsigned short* __restrict__ kn, const unsigned short* __restrict__ v,
    int n, int rpb, float* __restrict__ partial)
{
    __shared__ float kl[32][128], vl[32][128];
    const int t  = threadIdx.x;
    const int tx = t & 15;
    const int ty = t >> 4;
    const int r0 = blockIdx.x * rpb;
    const int r1 = min(n, r0 + rpb);

    float acc[8][8] = {};
    float sk[8] = {}, sv[8] = {};

    for (int base = r0; base < r1; base += 32) {
        float4 kz[4], vz[4];
        #pragma unroll
        for (int i = 0; i < 4; ++i) {
            int f = t + 256 * i;
            int rr = f >> 5, c4 = f & 31;
            int gr = base + rr;
            if (gr < r1) {
                us16x4 ku = *(const us16x4*)&kn[(size_t)gr * HID + c4 * 4];
                us16x4 vu = *(const us16x4*)&v [(size_t)gr * HID + c4 * 4];
                kz[i] = make_float4(bf2f(ku[0]), bf2f(ku[1]), bf2f(ku[2]), bf2f(ku[3]));
                vz[i] = make_float4(bf2f(vu[0]), bf2f(vu[1]), bf2f(vu[2]), bf2f(vu[3]));
            } else {
                kz[i] = make_float4(0, 0, 0, 0);
                vz[i] = make_float4(0, 0, 0, 0);
            }
        }
        __syncthreads();
        #pragma unroll
        for (int i = 0; i < 4; ++i) {
            int f = t + 256 * i;
            int rr = f >> 5, c4 = f & 31;
            *(float4*)&kl[rr][c4 * 4] = kz[i];
            *(float4*)&vl[rr][c4 * 4] = vz[i];
        }
        __syncthreads();
        #pragma unroll 8
        for (int rr = 0; rr < 32; ++rr) {
            float kk[8], vv[8];
            *(float4*)&kk[0] = *(float4*)&kl[rr][ty * 4];
            *(float4*)&kk[4] = *(float4*)&kl[rr][64 + ty * 4];
            *(float4*)&vv[0] = *(float4*)&vl[rr][tx * 4];
            *(float4*)&vv[4] = *(float4*)&vl[rr][64 + tx * 4];
            #pragma unroll
            for (int i = 0; i < 8; ++i)
                #pragma unroll
                for (int j = 0; j < 8; ++j)
                    acc[i][j] += kk[i] * vv[j];
            if (tx == 0) {
                #pragma unroll
                for (int i = 0; i < 8; ++i) sk[i] += kk[i];
            }
            if (ty == 0) {
                #pragma unroll
                for (int j = 0; j < 8; ++j) sv[j] += vv[j];
            }
        }
        __syncthreads();
    }

    float* pb = partial + (size_t)blockIdx.x * 16640;
    #pragma unroll
    for (int i = 0; i < 8; ++i) {
        int kd = (i < 4) ? (ty * 4 + i) : (64 + ty * 4 + i - 4);
        *(float4*)&pb[kd * HID + tx * 4]      = make_float4(acc[i][0], acc[i][1], acc[i][2], acc[i][3]);
        *(float4*)&pb[kd * HID + 64 + tx * 4] = make_float4(acc[i][4], acc[i][5], acc[i][6], acc[i][7]);
    }
    if (tx == 0) {
        #pragma unroll
        for (int i = 0; i < 8; ++i) {
            int kd = (i < 4) ? (ty * 4 + i) : (64 + ty * 4 + i - 4);
            pb[16384 + kd] = sk[i];
        }
    }
    if (ty == 0) {
        #pragma unroll
        for (int j = 0; j < 8; ++j) {
            int vd = (j < 4) ? (tx * 4 + j) : (64 + tx * 4 + j - 4);
            pb[16512 + vd] = sv[j];
        }
    }
}

// ------- kvs stage 2: sum partials -> bf16 transposed kvs (hi) + sums -------
__global__ __launch_bounds__(256) void reduce_kvs_p2(
    const float* __restrict__ partial, int nb,
    unsigned short* __restrict__ kvth, float* __restrict__ sums)
{
    __shared__ float lds[256];
    const int t    = threadIdx.x;
    const int o    = blockIdx.x * 64 + (t & 63);
    const int part = t >> 6;
    const int per  = (nb + 3) >> 2;
    const int b0   = part * per;
    const int b1   = min(nb, b0 + per);
    float s = 0.f;
    for (int b = b0; b < b1; ++b)
        s += partial[(size_t)b * 16640 + o];
    lds[t] = s;
    __syncthreads();
    if (part == 0) {
        float tot = lds[t] + lds[t + 64] + lds[t + 128] + lds[t + 192];
        if (o < 16384) {
            int k = o >> 7, nn = o & 127;
            kvth[nn * 128 + k] = f2bf(tot);
        } else {
            sums[o - 16384] = tot;
        }
    }
}

// ----------------------------- CSR construction -----------------------------
// pass 1: count + per-edge slot (atomic-return; coalesced epos write)
__global__ void cnt_hist_pos(const int* __restrict__ ei, int* __restrict__ cnt,
                             int* __restrict__ epos, int E)
{
    int e = blockIdx.x * 256 + threadIdx.x;
    if (e >= E) return;
    epos[e] = atomicAdd(&cnt[ei[E + e]], 1);
}

__global__ void rdeg_k(const int* __restrict__ cnt, float* __restrict__ rdeg, int n)
{
    int i = blockIdx.x * 256 + threadIdx.x;
    if (i < n) {
        int c = cnt[i];
        rdeg[i] = (c > 0) ? rsqrtf((float)c) : 0.f;
    }
}

// pass 2: atomic-free fill, destination-binned so stores stay L2-resident
__global__ void csr_fill_binned(const int* __restrict__ ei, const int* __restrict__ epos,
                                int* __restrict__ crow, int E, int c0, int c1)
{
    int e = blockIdx.x * 256 + threadIdx.x;
    if (e >= E) return;
    int c = ei[E + e];
    if (c < c0 || c >= c1) return;
    int p = epos[e];
    if (p < SLOTS) crow[(size_t)c * SLOTS + p] = ei[e];
}

// --------- fused: agg gather (fixed-stride CSR, fp8 g) + LN + ELU -----------
// writes bf16 h (out16) for inner layers, f32 (outf) for the final layer
__global__ __launch_bounds__(256) void gather_ln_elu(
    const int* __restrict__ cnt, const int* __restrict__ crow,
    const float* __restrict__ rdeg,
    const unsigned char* __restrict__ g, const float* __restrict__ accin,
    const float* __restrict__ gam, const float* __restrict__ bet,
    float* __restrict__ outf, unsigned short* __restrict__ out16, int n)
{
    int gw   = (int)((blockIdx.x * 256 + threadIdx.x) >> 6);
    int lane = threadIdx.x & 63;
    if (gw >= n) return;
    int cn = cnt[gw]; if (cn > SLOTS) cn = SLOTS;
    const int* cr = &crow[(size_t)gw * SLOTS];
    float rd = rdeg[gw];
    float2 a = *(const float2*)&accin[(size_t)gw * HID + lane * 2];

    int i = 0;
    for (; i + 3 < cn; i += 4) {
        int   r0 = cr[i],     r1 = cr[i + 1];
        int   r2 = cr[i + 2], r3 = cr[i + 3];
        float w0 = rd * rdeg[r0], w1 = rd * rdeg[r1];
        float w2 = rd * rdeg[r2], w3 = rd * rdeg[r3];
        unsigned short u0 = *(const unsigned short*)&g[(size_t)r0 * HID + lane * 2];
        unsigned short u1 = *(const unsigned short*)&g[(size_t)r1 * HID + lane * 2];
        unsigned short u2 = *(const unsigned short*)&g[(size_t)r2 * HID + lane * 2];
        unsigned short u3 = *(const unsigned short*)&g[(size_t)r3 * HID + lane * 2];
        f32x2 g0 = __builtin_amdgcn_cvt_pk_f32_fp8((int)u0, false);
        f32x2 g1 = __builtin_amdgcn_cvt_pk_f32_fp8((int)u1, false);
        f32x2 g2 = __builtin_amdgcn_cvt_pk_f32_fp8((int)u2, false);
        f32x2 g3 = __builtin_amdgcn_cvt_pk_f32_fp8((int)u3, false);
        a.x += w0 * g0[0] + w1 * g1[0] + w2 * g2[0] + w3 * g3[0];
        a.y += w0 * g0[1] + w1 * g1[1] + w2 * g2[1] + w3 * g3[1];
    }
    for (; i < cn; ++i) {
        int r0 = cr[i];
        float w0 = rd * rdeg[r0];
        unsigned short u0 = *(const unsigned short*)&g[(size_t)r0 * HID + lane * 2];
        f32x2 g0 = __builtin_amdgcn_cvt_pk_f32_fp8((int)u0, false);
        a.x += w0 * g0[0];
        a.y += w0 * g0[1];
    }

    float sm = a.x + a.y, ss = a.x * a.x + a.y * a.y;
    #pragma unroll
    for (int o = 32; o; o >>= 1) { sm += __shfl_xor(sm, o); ss += __shfl_xor(ss, o); }
    float mu  = sm * (1.f / 128.f);
    float var = ss * (1.f / 128.f) - mu * mu;
    float rs  = rsqrtf(var + EPS);
    float g0 = gam[lane * 2], g1 = gam[lane * 2 + 1];
    float b0 = bet[lane * 2], b1 = bet[lane * 2 + 1];
    float y0 = eluf((a.x - mu) * rs * g0 + b0);
    float y1 = eluf((a.y - mu) * rs * g1 + b1);
    if (out16) {
        ushort2 o2 = make_ushort2(f2bf(y0), f2bf(y1));
        *(ushort2*)&out16[(size_t)gw * HID + lane * 2] = o2;
    } else {
        *(float2*)&outf[(size_t)gw * HID + lane * 2] = make_float2(y0, y1);
    }
}

// ---------------------------------------------------------------------------
extern "C" void kernel_launch(void* const* d_in, const int* in_sizes, int n_in,
                              void* d_out, int out_size, void* d_ws, size_t ws_size,
                              hipStream_t stream)
{
    const float* x      = (const float*)d_in[0];
    const int*   ei     = (const int*)  d_in[1];
    const float* mlp_W0 = (const float*)d_in[2];
    const float* mlp_b0 = (const float*)d_in[3];
    const float* mlp_W  = (const float*)d_in[4];
    const float* mlp_b  = (const float*)d_in[5];
    const float* bn_g   = (const float*)d_in[6];
    const float* bn_b   = (const float*)d_in[7];
    const float* bn_m   = (const float*)d_in[8];
    const float* bn_v   = (const float*)d_in[9];
    const float* Wq = (const float*)d_in[10]; const float* bq = (const float*)d_in[11];
    const float* Wk = (const float*)d_in[12]; const float* bk = (const float*)d_in[13];
    const float* Wv = (const float*)d_in[14]; const float* bv = (const float*)d_in[15];
    const float* Wg = (const float*)d_in[16]; const float* bg = (const float*)d_in[17];
    const float* Wr = (const float*)d_in[18]; const float* br = (const float*)d_in[19];
    const float* ln_g = (const float*)d_in[20];
    const float* ln_b = (const float*)d_in[21];

    const int N = in_sizes[0] / INC;
    const int E = in_sizes[1] / 2;
    const size_t P = (size_t)N * HID;

    // workspace layout
    float* ws   = (float*)d_ws;
    float* mlpA = ws;                        // P f32 (MLP scratch)
    float* mlpB = mlpA + P;                  // P f32 (MLP scratch; kvs partials in layers)
    unsigned short* h16  = (unsigned short*)(mlpB + P);   // P bf16
    unsigned short* qb16 = h16 + P;                       // P bf16
    unsigned short* kb16 = qb16 + P;                      // P bf16
    unsigned short* vb16 = kb16 + P;                      // P bf16
    unsigned char*  gb8  = (unsigned char*)(vb16 + P);    // P fp8
    float* kvs  = (float*)(gb8 + P);         // 256 floats: [sum_kn][sum_v]
    int*   crow = (int*)(kvs + 256);         // N*SLOTS
    int*   cnt  = crow + (size_t)N * SLOTS;  // N
    int*   epos = cnt + N;                   // E
    float* rdeg = (float*)(epos + E);        // N
    unsigned short* wt = (unsigned short*)(rdeg + N);

    unsigned short *WTh[18], *WTl[18];
    int Ks[18];
    size_t woff = 0;
    for (int m = 0; m < 18; ++m) {
        int K = (m == 0) ? INC : HID;
        Ks[m] = K;
        WTh[m] = wt + woff;           woff += (size_t)128 * K;
        WTl[m] = wt + woff;           woff += (size_t)128 * K;
    }
    unsigned short* kvth = wt + woff; woff += 16384;
    float* acc = (float*)d_out;

    int nbk = NB_KVS;
    if ((size_t)nbk * 16640 > P) nbk = (int)(P / 16640);
    const int rpb = (N + nbk - 1) / nbk;

    const int gemmGrid = (N + 63) / 64;
    const int waveGrid = (N + 3) / 4;
    const int edgeGrid = (E + 255) / 256;
    const int nodeGrid = (N + 255) / 256;

    // --- weight pre-split ---
    WConvArgs wa;
    const float* srcs[18];
    srcs[0] = mlp_W0; srcs[1] = mlp_W; srcs[2] = mlp_W + (size_t)HID * HID;
    for (int l = 0; l < NLAYER; ++l) {
        const size_t wo = (size_t)l * HID * HID;
        srcs[3 + l * 5 + 0] = Wq + wo;
        srcs[3 + l * 5 + 1] = Wk + wo;
        srcs[3 + l * 5 + 2] = Wv + wo;
        srcs[3 + l * 5 + 3] = Wg + wo;
        srcs[3 + l * 5 + 4] = Wr + wo;
    }
    for (int m = 0; m < 18; ++m) {
        wa.src[m] = srcs[m]; wa.dh[m] = WTh[m]; wa.dl[m] = WTl[m]; wa.K[m] = Ks[m];
    }
    conv_weights<<<dim3(18, 8), 256, 0, stream>>>(wa);

    // --- CSR build: atomic count pass + binned atomic-free fill ---
    hipMemsetAsync(cnt, 0, (size_t)N * sizeof(int), stream);
    cnt_hist_pos<<<edgeGrid, 256, 0, stream>>>(ei, cnt, epos, E);
    rdeg_k<<<nodeGrid, 256, 0, stream>>>(cnt, rdeg, N);
    {
        int nper = (N + NBIN - 1) / NBIN;
        for (int b = 0; b < NBIN; ++b) {
            int c0 = b * nper;
            int c1 = (c0 + nper < N) ? c0 + nper : N;
            csr_fill_binned<<<edgeGrid, 256, 0, stream>>>(ei, epos, crow, E, c0, c1);
        }
    }

    // --- MLP: Linear -> BN(eval) -> ELU, x3 (last writes bf16 h) ---
    gemm_mlp<INC, false><<<gemmGrid, 256, 0, stream>>>(x, WTh[0], WTl[0], mlp_b0,
        bn_g, bn_b, bn_m, bn_v, mlpA, nullptr, N);
    gemm_mlp<HID, false><<<gemmGrid, 256, 0, stream>>>(mlpA, WTh[1], WTl[1], mlp_b,
        bn_g + HID, bn_b + HID, bn_m + HID, bn_v + HID, mlpB, nullptr, N);
    gemm_mlp<HID, true><<<gemmGrid, 256, 0, stream>>>(mlpB, WTh[2], WTl[2], mlp_b + HID,
        bn_g + 2 * HID, bn_b + 2 * HID, bn_m + 2 * HID, bn_v + 2 * HID, nullptr, h16, N);

    // --- TransConv layers ---
    for (int l = 0; l < NLAYER; ++l) {
        const int bo = l * HID;

        QKVGRArgs qa;
        for (int m = 0; m < 5; ++m) qa.wh[m] = WTh[3 + l * 5 + m];
        qa.bias[0] = bq + bo; qa.bias[1] = bk + bo; qa.bias[2] = bv + bo;
        qa.bias[3] = bg + bo; qa.bias[4] = br + bo;

        // h16 -> qn(bf16), kn(bf16), v(bf16), g(fp8), acc(r+res, f32)
        fused_qkvgr<<<gemmGrid, 256, 0, stream>>>(h16, qa,
            qb16, kb16, vb16, gb8, acc, N);

        // kvs = kn^T @ v (partials live in mlpB, dead after MLP)
        reduce_kvs_p1<<<nbk, 256, 0, stream>>>(kb16, vb16, N, rpb, mlpB);
        reduce_kvs_p2<<<260, 256, 0, stream>>>(mlpB, nbk, kvth, kvs);

        // acc += (qn @ kvs + sum_v) / (qn . sum_kn + N)
        gemm_num_combine<<<gemmGrid, 256, 0, stream>>>(qb16, kvth,
            kvs + 128, kvs, (float)N, acc, N);

        // fused gather (fp8 g) + LN + ELU; bf16 h for inner layers, f32 final
        bool last = (l == NLAYER - 1);
        gather_ln_elu<<<waveGrid, 256, 0, stream>>>(cnt, crow, rdeg,
            gb8, acc, ln_g + bo, ln_b + bo,
            last ? acc : nullptr, last ? nullptr : h16, N);
    }
}

// Round 9
// 1259.430 us; speedup vs baseline: 1.1166x; 1.1166x over previous
//
#include <hip/hip_runtime.h>
#include <cstdint>
#include <cstddef>

#define HID 128
#define INC 256
#define NLAYER 3
#define NB_KVS 768
#define SLOTS 96

static constexpr float EPS = 1e-5f;

typedef __attribute__((ext_vector_type(8))) short s16x8;
typedef __attribute__((ext_vector_type(4))) unsigned short us16x4;
typedef __attribute__((ext_vector_type(4))) float f32x4;
typedef __attribute__((ext_vector_type(2))) float f32x2;

__device__ __forceinline__ float eluf(float x) { return x > 0.f ? x : expm1f(x); }

__device__ __forceinline__ unsigned short f2bf(float x)
{
    unsigned u = __float_as_uint(x);
    u += 0x7FFFu + ((u >> 16) & 1u);
    return (unsigned short)(u >> 16);
}

__device__ __forceinline__ float bf2f(unsigned short u)
{
    return __uint_as_float(((unsigned)u) << 16);
}

__device__ __forceinline__ unsigned char f2fp8(float x)
{
    return (unsigned char)(__builtin_amdgcn_cvt_pk_fp8_f32(x, x, 0, false) & 0xFF);
}

// ---------------------------------------------------------------------------
// MLP GEMM, hi-only bf16: C16 = bf16(ELU(BN(A[n,K] @ W + bias))).
// IN32: A is f32 (layer 0, reads x); else A16 bf16.
// ---------------------------------------------------------------------------
template<int K, bool IN32>
__global__ __launch_bounds__(256) void gemm_mlp(
    const float* __restrict__ Af, const unsigned short* __restrict__ A16,
    const unsigned short* __restrict__ Wth,
    const float* __restrict__ bias,
    const float* __restrict__ bng, const float* __restrict__ bnb,
    const float* __restrict__ bnm, const float* __restrict__ bnv,
    unsigned short* __restrict__ C16, int n)
{
    __shared__ unsigned short Ah[64 * 64], Wh[128 * 64];   // 8KB + 16KB
    const int t = threadIdx.x;
    const int l = t & 63;
    const int w = t >> 6;
    const int l15 = l & 15;
    const int row0 = blockIdx.x * 64;

    char* cAh = (char*)Ah;
    char* cWh = (char*)Wh;

    f32x4 acc[8] = {};

    for (int kc = 0; kc < K; kc += 64) {
        if (IN32) {
            #pragma unroll
            for (int i = 0; i < 4; ++i) {
                int f = t + 256 * i;
                int r = f >> 4, c4 = f & 15;
                int gr = row0 + r; if (gr > n - 1) gr = n - 1;
                float4 a4 = *(const float4*)&Af[(size_t)gr * K + kc + c4 * 4];
                int byte = r * 128 + (((c4 >> 1) * 16) ^ ((r & 7) << 4)) + (c4 & 1) * 8;
                *(us16x4*)(cAh + byte) =
                    (us16x4){f2bf(a4.x), f2bf(a4.y), f2bf(a4.z), f2bf(a4.w)};
            }
        } else {
            #pragma unroll
            for (int i = 0; i < 2; ++i) {
                int f = t + 256 * i;
                int r = f >> 3, c8 = f & 7;
                int gr = row0 + r; if (gr > n - 1) gr = n - 1;
                int byte = r * 128 + ((c8 * 16) ^ ((r & 7) << 4));
                *(s16x8*)(cAh + byte) = *(const s16x8*)&A16[(size_t)gr * K + kc + c8 * 8];
            }
        }
        #pragma unroll
        for (int i = 0; i < 4; ++i) {
            int f = t + 256 * i;
            int nr = f >> 3, c8 = f & 7;
            size_t gsrc = (size_t)nr * K + kc + c8 * 8;
            int byte = nr * 128 + ((c8 * 16) ^ ((nr & 7) << 4));
            *(s16x8*)(cWh + byte) = *(const s16x8*)&Wth[gsrc];
        }
        __syncthreads();
        #pragma unroll
        for (int ks = 0; ks < 2; ++ks) {
            int jA = ks * 4 + (l >> 4);
            int ar = w * 16 + l15;
            int aoff = ar * 128 + ((jA * 16) ^ ((ar & 7) << 4));
            s16x8 fah = *(s16x8*)(cAh + aoff);
            #pragma unroll
            for (int nt = 0; nt < 8; ++nt) {
                int nr = nt * 16 + l15;
                int boff = nr * 128 + ((jA * 16) ^ ((nr & 7) << 4));
                acc[nt] = __builtin_amdgcn_mfma_f32_16x16x32_bf16(fah, *(s16x8*)(cWh + boff), acc[nt], 0, 0, 0);
            }
        }
        __syncthreads();
    }

    const int rbase = row0 + w * 16 + ((l >> 4) << 2);
    #pragma unroll
    for (int nt = 0; nt < 8; ++nt) {
        int col = nt * 16 + l15;
        float bb = bias[col];
        float gm = bng[col], bt = bnb[col], mn = bnm[col], vr = bnv[col];
        #pragma unroll
        for (int r = 0; r < 4; ++r) {
            int row = rbase + r;
            if (row < n) {
                float o = acc[nt][r] + bb;
                o = eluf((o - mn) * rsqrtf(vr + EPS) * gm + bt);
                C16[(size_t)row * HID + col] = f2bf(o);
            }
        }
    }
}

// ---------------------------------------------------------------------------
// Fused per-layer QKVGR, hi-only bf16, double-buffered W staging (R8, passed).
// ---------------------------------------------------------------------------
struct QKVGRArgs {
    const unsigned short* wh[5];
    const float* bias[5];
};

__global__ __launch_bounds__(256) void fused_qkvgr(
    const unsigned short* __restrict__ A16, QKVGRArgs ar,
    unsigned short* __restrict__ qb16, unsigned short* __restrict__ kb16,
    unsigned short* __restrict__ vb16,
    unsigned char* __restrict__ gb8, float* __restrict__ accout, int n)
{
    __shared__ char smem[81920];
    char* cA = smem;                                      // 16KB
    char* wb0 = smem + 16384;                             // 32KB
    char* wb1 = smem + 49152;                             // 32KB

    const int t = threadIdx.x;
    const int l = t & 63;
    const int w = t >> 6;
    const int l15 = l & 15;
    const int row0 = blockIdx.x * 64;

    #pragma unroll
    for (int i = 0; i < 4; ++i) {
        int f = t + 256 * i;
        int r = f >> 4, c8 = f & 15;
        int gr = row0 + r; if (gr > n - 1) gr = n - 1;
        int byte = r * 256 + ((c8 * 16) ^ ((r & 7) << 4));
        *(s16x8*)(cA + byte) = *(const s16x8*)&A16[(size_t)gr * HID + c8 * 8];
    }
    __syncthreads();

    s16x8 fah[4];
    {
        const int arow = w * 16 + l15;
        #pragma unroll
        for (int ks = 0; ks < 4; ++ks) {
            int aoff = arow * 256 + (((ks * 64) + (l >> 4) * 16) ^ ((arow & 7) << 4));
            fah[ks] = *(s16x8*)(cA + aoff);
        }
    }
    {
        const unsigned short* wh = ar.wh[0];
        #pragma unroll
        for (int i = 0; i < 8; ++i) {
            int f = t + 256 * i;
            int nr = f >> 4, c8 = f & 15;
            int byte = nr * 256 + ((c8 * 16) ^ ((nr & 7) << 4));
            *(s16x8*)(wb0 + byte) = *(const s16x8*)&wh[(size_t)nr * HID + c8 * 8];
        }
    }
    __syncthreads();

    const int rbase = row0 + w * 16 + ((l >> 4) << 2);

    for (int m = 0; m < 5; ++m) {
        char* cw = (m & 1) ? wb1 : wb0;
        if (m < 4) {
            char* nw = (m & 1) ? wb0 : wb1;
            const unsigned short* wh = ar.wh[m + 1];
            #pragma unroll
            for (int i = 0; i < 8; ++i) {
                int f = t + 256 * i;
                int nr = f >> 4, c8 = f & 15;
                int byte = nr * 256 + ((c8 * 16) ^ ((nr & 7) << 4));
                *(s16x8*)(nw + byte) = *(const s16x8*)&wh[(size_t)nr * HID + c8 * 8];
            }
        }

        f32x4 acc[8] = {};
        #pragma unroll
        for (int ks = 0; ks < 4; ++ks) {
            #pragma unroll
            for (int nt = 0; nt < 8; ++nt) {
                int nr = nt * 16 + l15;
                int boff = nr * 256 + (((ks * 64) + (l >> 4) * 16) ^ ((nr & 7) << 4));
                acc[nt] = __builtin_amdgcn_mfma_f32_16x16x32_bf16(fah[ks], *(s16x8*)(cw + boff), acc[nt], 0, 0, 0);
            }
        }

        float bb[8];
        #pragma unroll
        for (int nt = 0; nt < 8; ++nt) bb[nt] = ar.bias[m][nt * 16 + l15];

        if (m <= 1) {
            unsigned short* out = (m == 0) ? qb16 : kb16;
            #pragma unroll
            for (int r = 0; r < 4; ++r) {
                float ss = 0.f;
                #pragma unroll
                for (int nt = 0; nt < 8; ++nt) {
                    float o = acc[nt][r] + bb[nt];
                    ss += o * o;
                }
                ss += __shfl_xor(ss, 1); ss += __shfl_xor(ss, 2);
                ss += __shfl_xor(ss, 4); ss += __shfl_xor(ss, 8);
                float rn = rsqrtf(ss);
                int row = rbase + r;
                if (row < n) {
                    #pragma unroll
                    for (int nt = 0; nt < 8; ++nt)
                        out[(size_t)row * HID + nt * 16 + l15] = f2bf((acc[nt][r] + bb[nt]) * rn);
                }
            }
        } else if (m == 2) {
            #pragma unroll
            for (int r = 0; r < 4; ++r) {
                int row = rbase + r;
                if (row < n) {
                    #pragma unroll
                    for (int nt = 0; nt < 8; ++nt)
                        vb16[(size_t)row * HID + nt * 16 + l15] = f2bf(acc[nt][r] + bb[nt]);
                }
            }
        } else if (m == 3) {
            #pragma unroll
            for (int r = 0; r < 4; ++r) {
                int row = rbase + r;
                if (row < n) {
                    #pragma unroll
                    for (int nt = 0; nt < 8; ++nt)
                        gb8[(size_t)row * HID + nt * 16 + l15] = f2fp8(acc[nt][r] + bb[nt]);
                }
            }
        } else {
            #pragma unroll
            for (int r = 0; r < 4; ++r) {
                int row = rbase + r;
                if (row < n) {
                    #pragma unroll
                    for (int nt = 0; nt < 8; ++nt) {
                        int col = nt * 16 + l15;
                        accout[(size_t)row * HID + col] =
                            acc[nt][r] + bb[nt] + bf2f(A16[(size_t)row * HID + col]);
                    }
                }
            }
        }
        __syncthreads();
    }
}

// ---------------------------------------------------------------------------
// num+combine: accio += (qn @ kvs + sum_v) / (qn . sum_kn + nf)
// ---------------------------------------------------------------------------
__global__ __launch_bounds__(256) void gemm_num_combine(
    const unsigned short* __restrict__ A16,
    const unsigned short* __restrict__ Bth,
    const float* __restrict__ sumv, const float* __restrict__ snk,
    float nf, float* __restrict__ accio, int n)
{
    __shared__ char smem[16384 + 32768];
    char* cA = smem;
    char* cW = smem + 16384;

    const int t = threadIdx.x;
    const int l = t & 63;
    const int w = t >> 6;
    const int l15 = l & 15;
    const int row0 = blockIdx.x * 64;

    #pragma unroll
    for (int i = 0; i < 4; ++i) {
        int f = t + 256 * i;
        int r = f >> 4, c8 = f & 15;
        int gr = row0 + r; if (gr > n - 1) gr = n - 1;
        int byte = r * 256 + ((c8 * 16) ^ ((r & 7) << 4));
        *(s16x8*)(cA + byte) = *(const s16x8*)&A16[(size_t)gr * HID + c8 * 8];
    }
    #pragma unroll
    for (int i = 0; i < 8; ++i) {
        int f = t + 256 * i;
        int nr = f >> 4, c8 = f & 15;
        int byte = nr * 256 + ((c8 * 16) ^ ((nr & 7) << 4));
        *(s16x8*)(cW + byte) = *(const s16x8*)&Bth[(size_t)nr * HID + c8 * 8];
    }
    __syncthreads();

    f32x4 acc[8] = {};
    const int arow = w * 16 + l15;
    #pragma unroll
    for (int ks = 0; ks < 4; ++ks) {
        int aoff = arow * 256 + (((ks * 64) + (l >> 4) * 16) ^ ((arow & 7) << 4));
        s16x8 fa = *(s16x8*)(cA + aoff);
        #pragma unroll
        for (int nt = 0; nt < 8; ++nt) {
            int nr = nt * 16 + l15;
            int boff = nr * 256 + (((ks * 64) + (l >> 4) * 16) ^ ((nr & 7) << 4));
            acc[nt] = __builtin_amdgcn_mfma_f32_16x16x32_bf16(fa, *(s16x8*)(cW + boff), acc[nt], 0, 0, 0);
        }
    }

    const int rbase = row0 + w * 16 + ((l >> 4) << 2);
    float bb[8], skn[8];
    #pragma unroll
    for (int nt = 0; nt < 8; ++nt) {
        bb[nt]  = sumv[nt * 16 + l15];
        skn[nt] = snk[nt * 16 + l15];
    }
    #pragma unroll
    for (int r = 0; r < 4; ++r) {
        int row = rbase + r;
        float p = 0.f;
        if (row < n) {
            #pragma unroll
            for (int nt = 0; nt < 8; ++nt)
                p += bf2f(A16[(size_t)row * HID + nt * 16 + l15]) * skn[nt];
        }
        p += __shfl_xor(p, 1); p += __shfl_xor(p, 2);
        p += __shfl_xor(p, 4); p += __shfl_xor(p, 8);
        float dinv = 1.f / (p + nf);
        if (row < n) {
            #pragma unroll
            for (int nt = 0; nt < 8; ++nt) {
                size_t idx = (size_t)row * HID + nt * 16 + l15;
                accio[idx] += (acc[nt][r] + bb[nt]) * dinv;
            }
        }
    }
}

// ------------------- weight pre-convert (+transpose), hi-only ---------------
struct WConvArgs {
    const float* src[18];
    unsigned short* dh[18];
    int K[18];
};

__global__ void conv_weights(WConvArgs a)
{
    int m = blockIdx.x;
    const float* s = a.src[m];
    unsigned short* dh = a.dh[m];
    int K = a.K[m];
    int tot = 128 * K;
    int slice = (tot + gridDim.y - 1) / gridDim.y;
    int i0 = blockIdx.y * slice;
    int i1 = min(tot, i0 + slice);
    for (int idx = i0 + threadIdx.x; idx < i1; idx += 256) {
        int nn = idx / K, k = idx - nn * K;
        dh[idx] = f2bf(s[(size_t)k * 128 + nn]);
    }
}

// ---------------- kvs stage 1: per-block partial kn^T @ v (bf16 in) ---------
__global__ __launch_bounds__(256) void reduce_kvs_p1(
    const unsigned short* __restrict__ kn, const unsigned short* __restrict__ v,
    int n, int rpb, float* __restrict__ partial)
{
    __shared__ float kl[32][128], vl[32][128];
    const int t  = threadIdx.x;
    const int tx = t & 15;
    const int ty = t >> 4;
    const int r0 = blockIdx.x * rpb;
    const int r1 = min(n, r0 + rpb);

    float acc[8][8] = {};
    float sk[8] = {}, sv[8] = {};

    for (int base = r0; base < r1; base += 32) {
        float4 kz[4], vz[4];
        #pragma unroll
        for (int i = 0; i < 4; ++i) {
            int f = t + 256 * i;
            int rr = f >> 5, c4 = f & 31;
            int gr = base + rr;
            if (gr < r1) {
                us16x4 ku = *(const us16x4*)&kn[(size_t)gr * HID + c4 * 4];
                us16x4 vu = *(const us16x4*)&v [(size_t)gr * HID + c4 * 4];
                kz[i] = make_float4(bf2f(ku[0]), bf2f(ku[1]), bf2f(ku[2]), bf2f(ku[3]));
                vz[i] = make_float4(bf2f(vu[0]), bf2f(vu[1]), bf2f(vu[2]), bf2f(vu[3]));
            } else {
                kz[i] = make_float4(0, 0, 0, 0);
                vz[i] = make_float4(0, 0, 0, 0);
            }
        }
        __syncthreads();
        #pragma unroll
        for (int i = 0; i < 4; ++i) {
            int f = t + 256 * i;
            int rr = f >> 5, c4 = f & 31;
            *(float4*)&kl[rr][c4 * 4] = kz[i];
            *(float4*)&vl[rr][c4 * 4] = vz[i];
        }
        __syncthreads();
        #pragma unroll 8
        for (int rr = 0; rr < 32; ++rr) {
            float kk[8], vv[8];
            *(float4*)&kk[0] = *(float4*)&kl[rr][ty * 4];
            *(float4*)&kk[4] = *(float4*)&kl[rr][64 + ty * 4];
            *(float4*)&vv[0] = *(float4*)&vl[rr][tx * 4];
            *(float4*)&vv[4] = *(float4*)&vl[rr][64 + tx * 4];
            #pragma unroll
            for (int i = 0; i < 8; ++i)
                #pragma unroll
                for (int j = 0; j < 8; ++j)
                    acc[i][j] += kk[i] * vv[j];
            if (tx == 0) {
                #pragma unroll
                for (int i = 0; i < 8; ++i) sk[i] += kk[i];
            }
            if (ty == 0) {
                #pragma unroll
                for (int j = 0; j < 8; ++j) sv[j] += vv[j];
            }
        }
        __syncthreads();
    }

    float* pb = partial + (size_t)blockIdx.x * 16640;
    #pragma unroll
    for (int i = 0; i < 8; ++i) {
        int kd = (i < 4) ? (ty * 4 + i) : (64 + ty * 4 + i - 4);
        *(float4*)&pb[kd * HID + tx * 4]      = make_float4(acc[i][0], acc[i][1], acc[i][2], acc[i][3]);
        *(float4*)&pb[kd * HID + 64 + tx * 4] = make_float4(acc[i][4], acc[i][5], acc[i][6], acc[i][7]);
    }
    if (tx == 0) {
        #pragma unroll
        for (int i = 0; i < 8; ++i) {
            int kd = (i < 4) ? (ty * 4 + i) : (64 + ty * 4 + i - 4);
            pb[16384 + kd] = sk[i];
        }
    }
    if (ty == 0) {
        #pragma unroll
        for (int j = 0; j < 8; ++j) {
            int vd = (j < 4) ? (tx * 4 + j) : (64 + tx * 4 + j - 4);
            pb[16512 + vd] = sv[j];
        }
    }
}

// ------- kvs stage 2: sum partials -> bf16 transposed kvs (hi) + sums -------
__global__ __launch_bounds__(256) void reduce_kvs_p2(
    const float* __restrict__ partial, int nb,
    unsigned short* __restrict__ kvth, float* __restrict__ sums)
{
    __shared__ float lds[256];
    const int t    = threadIdx.x;
    const int o    = blockIdx.x * 64 + (t & 63);
    const int part = t >> 6;
    const int per  = (nb + 3) >> 2;
    const int b0   = part * per;
    const int b1   = min(nb, b0 + per);
    float s = 0.f;
    for (int b = b0; b < b1; ++b)
        s += partial[(size_t)b * 16640 + o];
    lds[t] = s;
    __syncthreads();
    if (part == 0) {
        float tot = lds[t] + lds[t + 64] + lds[t + 128] + lds[t + 192];
        if (o < 16384) {
            int k = o >> 7, nn = o & 127;
            kvth[nn * 128 + k] = f2bf(tot);
        } else {
            sums[o - 16384] = tot;
        }
    }
}

// -------------- one-pass fixed-stride CSR (nontemporal store) ---------------
__global__ void csr_fill_fixed(const int* __restrict__ ei, int* __restrict__ cur,
                               int* __restrict__ crow, int E)
{
    int e = blockIdx.x * 256 + threadIdx.x;
    if (e >= E) return;
    int r = ei[e], c = ei[E + e];
    int p = atomicAdd(&cur[c], 1);
    if (p < SLOTS) __builtin_nontemporal_store(r, &crow[(size_t)c * SLOTS + p]);
}

__global__ void rdeg_k(const int* __restrict__ cur, float* __restrict__ rdeg, int n)
{
    int i = blockIdx.x * 256 + threadIdx.x;
    if (i < n) {
        int c = cur[i];
        rdeg[i] = (c > 0) ? rsqrtf((float)c) : 0.f;
    }
}

// --------- fused gather + LN + ELU: 2 nodes/wave, dword fp8 loads -----------
__global__ __launch_bounds__(256) void gather_ln_elu2(
    const int* __restrict__ cnt, const int* __restrict__ crow,
    const float* __restrict__ rdeg,
    const unsigned char* __restrict__ g, const float* __restrict__ accin,
    const float* __restrict__ gam, const float* __restrict__ bet,
    float* __restrict__ outf, unsigned short* __restrict__ out16, int n)
{
    int wid  = (int)((blockIdx.x * 256 + threadIdx.x) >> 6);
    int half = (threadIdx.x >> 5) & 1;
    int li   = threadIdx.x & 31;
    int node = wid * 2 + half;
    if (node >= n) return;

    int cn = cnt[node]; if (cn > SLOTS) cn = SLOTS;
    const int* cr = &crow[(size_t)node * SLOTS];
    float rd = rdeg[node];
    float4 a = *(const float4*)&accin[(size_t)node * HID + li * 4];

    int i = 0;
    for (; i + 3 < cn; i += 4) {
        int   r0 = cr[i],     r1 = cr[i + 1];
        int   r2 = cr[i + 2], r3 = cr[i + 3];
        float w0 = rd * rdeg[r0], w1 = rd * rdeg[r1];
        float w2 = rd * rdeg[r2], w3 = rd * rdeg[r3];
        unsigned u0 = *(const unsigned*)&g[(size_t)r0 * HID + li * 4];
        unsigned u1 = *(const unsigned*)&g[(size_t)r1 * HID + li * 4];
        unsigned u2 = *(const unsigned*)&g[(size_t)r2 * HID + li * 4];
        unsigned u3 = *(const unsigned*)&g[(size_t)r3 * HID + li * 4];
        f32x2 p0l = __builtin_amdgcn_cvt_pk_f32_fp8((int)u0, false);
        f32x2 p0h = __builtin_amdgcn_cvt_pk_f32_fp8((int)u0, true);
        f32x2 p1l = __builtin_amdgcn_cvt_pk_f32_fp8((int)u1, false);
        f32x2 p1h = __builtin_amdgcn_cvt_pk_f32_fp8((int)u1, true);
        f32x2 p2l = __builtin_amdgcn_cvt_pk_f32_fp8((int)u2, false);
        f32x2 p2h = __builtin_amdgcn_cvt_pk_f32_fp8((int)u2, true);
        f32x2 p3l = __builtin_amdgcn_cvt_pk_f32_fp8((int)u3, false);
        f32x2 p3h = __builtin_amdgcn_cvt_pk_f32_fp8((int)u3, true);
        a.x += w0 * p0l[0] + w1 * p1l[0] + w2 * p2l[0] + w3 * p3l[0];
        a.y += w0 * p0l[1] + w1 * p1l[1] + w2 * p2l[1] + w3 * p3l[1];
        a.z += w0 * p0h[0] + w1 * p1h[0] + w2 * p2h[0] + w3 * p3h[0];
        a.w += w0 * p0h[1] + w1 * p1h[1] + w2 * p2h[1] + w3 * p3h[1];
    }
    for (; i < cn; ++i) {
        int r0 = cr[i];
        float w0 = rd * rdeg[r0];
        unsigned u0 = *(const unsigned*)&g[(size_t)r0 * HID + li * 4];
        f32x2 p0l = __builtin_amdgcn_cvt_pk_f32_fp8((int)u0, false);
        f32x2 p0h = __builtin_amdgcn_cvt_pk_f32_fp8((int)u0, true);
        a.x += w0 * p0l[0]; a.y += w0 * p0l[1];
        a.z += w0 * p0h[0]; a.w += w0 * p0h[1];
    }

    float sm = a.x + a.y + a.z + a.w;
    float ss = a.x * a.x + a.y * a.y + a.z * a.z + a.w * a.w;
    #pragma unroll
    for (int o = 16; o; o >>= 1) { sm += __shfl_xor(sm, o); ss += __shfl_xor(ss, o); }
    float mu  = sm * (1.f / 128.f);
    float var = ss * (1.f / 128.f) - mu * mu;
    float rs  = rsqrtf(var + EPS);
    float4 gm = *(const float4*)&gam[li * 4];
    float4 bt = *(const float4*)&bet[li * 4];
    float y0 = eluf((a.x - mu) * rs * gm.x + bt.x);
    float y1 = eluf((a.y - mu) * rs * gm.y + bt.y);
    float y2 = eluf((a.z - mu) * rs * gm.z + bt.z);
    float y3 = eluf((a.w - mu) * rs * gm.w + bt.w);
    if (out16) {
        us16x4 o4 = (us16x4){f2bf(y0), f2bf(y1), f2bf(y2), f2bf(y3)};
        *(us16x4*)&out16[(size_t)node * HID + li * 4] = o4;
    } else {
        *(float4*)&outf[(size_t)node * HID + li * 4] = make_float4(y0, y1, y2, y3);
    }
}

// ---------------------------------------------------------------------------
extern "C" void kernel_launch(void* const* d_in, const int* in_sizes, int n_in,
                              void* d_out, int out_size, void* d_ws, size_t ws_size,
                              hipStream_t stream)
{
    const float* x      = (const float*)d_in[0];
    const int*   ei     = (const int*)  d_in[1];
    const float* mlp_W0 = (const float*)d_in[2];
    const float* mlp_b0 = (const float*)d_in[3];
    const float* mlp_W  = (const float*)d_in[4];
    const float* mlp_b  = (const float*)d_in[5];
    const float* bn_g   = (const float*)d_in[6];
    const float* bn_b   = (const float*)d_in[7];
    const float* bn_m   = (const float*)d_in[8];
    const float* bn_v   = (const float*)d_in[9];
    const float* Wq = (const float*)d_in[10]; const float* bq = (const float*)d_in[11];
    const float* Wk = (const float*)d_in[12]; const float* bk = (const float*)d_in[13];
    const float* Wv = (const float*)d_in[14]; const float* bv = (const float*)d_in[15];
    const float* Wg = (const float*)d_in[16]; const float* bg = (const float*)d_in[17];
    const float* Wr = (const float*)d_in[18]; const float* br = (const float*)d_in[19];
    const float* ln_g = (const float*)d_in[20];
    const float* ln_b = (const float*)d_in[21];

    const int N = in_sizes[0] / INC;
    const int E = in_sizes[1] / 2;
    const size_t P = (size_t)N * HID;

    // workspace layout
    float* ws   = (float*)d_ws;
    float* part = ws;                        // P f32 (kvs partials)
    unsigned short* h16  = (unsigned short*)(part + P);   // P bf16
    unsigned short* qb16 = h16 + P;                       // P bf16
    unsigned short* kb16 = qb16 + P;                      // P bf16 (also MLP scratch A)
    unsigned short* vb16 = kb16 + P;                      // P bf16 (also MLP scratch B)
    unsigned char*  gb8  = (unsigned char*)(vb16 + P);    // P fp8
    float* kvs  = (float*)(gb8 + P);         // 256 floats: [sum_kn][sum_v]
    int*   crow = (int*)(kvs + 256);         // N*SLOTS
    int*   cnt  = crow + (size_t)N * SLOTS;  // N
    float* rdeg = (float*)(cnt + N);         // N
    unsigned short* wt = (unsigned short*)(rdeg + N);

    unsigned short* WTh[18];
    int Ks[18];
    size_t woff = 0;
    for (int m = 0; m < 18; ++m) {
        int K = (m == 0) ? INC : HID;
        Ks[m] = K;
        WTh[m] = wt + woff;           woff += (size_t)128 * K;
    }
    unsigned short* kvth = wt + woff; woff += 16384;
    float* acc = (float*)d_out;

    int nbk = NB_KVS;
    if ((size_t)nbk * 16640 > P) nbk = (int)(P / 16640);
    const int rpb = (N + nbk - 1) / nbk;

    const int gemmGrid = (N + 63) / 64;
    const int gw2Grid  = (N + 7) / 8;
    const int edgeGrid = (E + 255) / 256;
    const int nodeGrid = (N + 255) / 256;

    // --- weight pre-convert (hi-only, transposed) ---
    WConvArgs wa;
    const float* srcs[18];
    srcs[0] = mlp_W0; srcs[1] = mlp_W; srcs[2] = mlp_W + (size_t)HID * HID;
    for (int l = 0; l < NLAYER; ++l) {
        const size_t wo = (size_t)l * HID * HID;
        srcs[3 + l * 5 + 0] = Wq + wo;
        srcs[3 + l * 5 + 1] = Wk + wo;
        srcs[3 + l * 5 + 2] = Wv + wo;
        srcs[3 + l * 5 + 3] = Wg + wo;
        srcs[3 + l * 5 + 4] = Wr + wo;
    }
    for (int m = 0; m < 18; ++m) {
        wa.src[m] = srcs[m]; wa.dh[m] = WTh[m]; wa.K[m] = Ks[m];
    }
    conv_weights<<<dim3(18, 8), 256, 0, stream>>>(wa);

    // --- CSR build: single-pass atomic fixed-stride fill (nt stores) ---
    hipMemsetAsync(cnt, 0, (size_t)N * sizeof(int), stream);
    csr_fill_fixed<<<edgeGrid, 256, 0, stream>>>(ei, cnt, crow, E);
    rdeg_k<<<nodeGrid, 256, 0, stream>>>(cnt, rdeg, N);

    // --- MLP: hi-only bf16, bf16 intermediates (reuse kb16/vb16) ---
    gemm_mlp<INC, true><<<gemmGrid, 256, 0, stream>>>(x, nullptr, WTh[0], mlp_b0,
        bn_g, bn_b, bn_m, bn_v, kb16, N);
    gemm_mlp<HID, false><<<gemmGrid, 256, 0, stream>>>(nullptr, kb16, WTh[1], mlp_b,
        bn_g + HID, bn_b + HID, bn_m + HID, bn_v + HID, vb16, N);
    gemm_mlp<HID, false><<<gemmGrid, 256, 0, stream>>>(nullptr, vb16, WTh[2], mlp_b + HID,
        bn_g + 2 * HID, bn_b + 2 * HID, bn_m + 2 * HID, bn_v + 2 * HID, h16, N);

    // --- TransConv layers ---
    for (int l = 0; l < NLAYER; ++l) {
        const int bo = l * HID;

        QKVGRArgs qa;
        for (int m = 0; m < 5; ++m) qa.wh[m] = WTh[3 + l * 5 + m];
        qa.bias[0] = bq + bo; qa.bias[1] = bk + bo; qa.bias[2] = bv + bo;
        qa.bias[3] = bg + bo; qa.bias[4] = br + bo;

        // h16 -> qn(bf16), kn(bf16), v(bf16), g(fp8), acc(r+res, f32)
        fused_qkvgr<<<gemmGrid, 256, 0, stream>>>(h16, qa,
            qb16, kb16, vb16, gb8, acc, N);

        // kvs = kn^T @ v
        reduce_kvs_p1<<<nbk, 256, 0, stream>>>(kb16, vb16, N, rpb, part);
        reduce_kvs_p2<<<260, 256, 0, stream>>>(part, nbk, kvth, kvs);

        // acc += (qn @ kvs + sum_v) / (qn . sum_kn + N)
        gemm_num_combine<<<gemmGrid, 256, 0, stream>>>(qb16, kvth,
            kvs + 128, kvs, (float)N, acc, N);

        // fused gather (fp8 g, 2 nodes/wave) + LN + ELU
        bool last = (l == NLAYER - 1);
        gather_ln_elu2<<<gw2Grid, 256, 0, stream>>>(cnt, crow, rdeg,
            gb8, acc, ln_g + bo, ln_b + bo,
            last ? acc : nullptr, last ? nullptr : h16, N);
    }
}

// Round 10
// 1094.436 us; speedup vs baseline: 1.2850x; 1.1508x over previous
//
#include <hip/hip_runtime.h>
#include <cstdint>
#include <cstddef>

#define HID 128
#define INC 256
#define NLAYER 3
#define NB_KVS 768
#define SLOTS 96

static constexpr float EPS = 1e-5f;

typedef __attribute__((ext_vector_type(8))) short s16x8;
typedef __attribute__((ext_vector_type(4))) unsigned short us16x4;
typedef __attribute__((ext_vector_type(4))) float f32x4;
typedef __attribute__((ext_vector_type(2))) float f32x2;

__device__ __forceinline__ float eluf(float x) { return x > 0.f ? x : expm1f(x); }

__device__ __forceinline__ unsigned short f2bf(float x)
{
    unsigned u = __float_as_uint(x);
    u += 0x7FFFu + ((u >> 16) & 1u);
    return (unsigned short)(u >> 16);
}

__device__ __forceinline__ float bf2f(unsigned short u)
{
    return __uint_as_float(((unsigned)u) << 16);
}

__device__ __forceinline__ unsigned char f2fp8(float x)
{
    return (unsigned char)(__builtin_amdgcn_cvt_pk_fp8_f32(x, x, 0, false) & 0xFF);
}

// ---- CSR co-run side-job: blocks past hostGrid fill an edge range ----------
__device__ __forceinline__ bool csr_side(int hostGrid, const int* __restrict__ ei,
                                         int* cnt, int* crow, int Etot, int e0, int e1)
{
    if ((int)blockIdx.x < hostGrid) return false;
    int e = e0 + (int)(blockIdx.x - hostGrid) * 256 + (int)threadIdx.x;
    if (e < e1) {
        int r = ei[e], c = ei[Etot + e];
        int p = atomicAdd(&cnt[c], 1);
        if (p < SLOTS) crow[(size_t)c * SLOTS + p] = r;
    }
    return true;
}

// ---------------------------------------------------------------------------
// MLP GEMM, hi-only bf16: C16 = bf16(ELU(BN(A[n,K] @ W + bias))).
// IN32: A is f32 (layer 0, reads x); else A16 bf16.  Carries a CSR chunk.
// ---------------------------------------------------------------------------
template<int K, bool IN32>
__global__ __launch_bounds__(256) void gemm_mlp(
    const float* __restrict__ Af, const unsigned short* __restrict__ A16,
    const unsigned short* __restrict__ Wth,
    const float* __restrict__ bias,
    const float* __restrict__ bng, const float* __restrict__ bnb,
    const float* __restrict__ bnm, const float* __restrict__ bnv,
    unsigned short* __restrict__ C16, int n,
    const int* __restrict__ ei, int* cntp, int* crowp, int Etot, int e0, int e1,
    int hostGrid)
{
    if (csr_side(hostGrid, ei, cntp, crowp, Etot, e0, e1)) return;

    __shared__ unsigned short Ah[64 * 64], Wh[128 * 64];
    const int t = threadIdx.x;
    const int l = t & 63;
    const int w = t >> 6;
    const int l15 = l & 15;
    const int row0 = blockIdx.x * 64;

    char* cAh = (char*)Ah;
    char* cWh = (char*)Wh;

    f32x4 acc[8] = {};

    for (int kc = 0; kc < K; kc += 64) {
        if (IN32) {
            #pragma unroll
            for (int i = 0; i < 4; ++i) {
                int f = t + 256 * i;
                int r = f >> 4, c4 = f & 15;
                int gr = row0 + r; if (gr > n - 1) gr = n - 1;
                float4 a4 = *(const float4*)&Af[(size_t)gr * K + kc + c4 * 4];
                int byte = r * 128 + (((c4 >> 1) * 16) ^ ((r & 7) << 4)) + (c4 & 1) * 8;
                *(us16x4*)(cAh + byte) =
                    (us16x4){f2bf(a4.x), f2bf(a4.y), f2bf(a4.z), f2bf(a4.w)};
            }
        } else {
            #pragma unroll
            for (int i = 0; i < 2; ++i) {
                int f = t + 256 * i;
                int r = f >> 3, c8 = f & 7;
                int gr = row0 + r; if (gr > n - 1) gr = n - 1;
                int byte = r * 128 + ((c8 * 16) ^ ((r & 7) << 4));
                *(s16x8*)(cAh + byte) = *(const s16x8*)&A16[(size_t)gr * K + kc + c8 * 8];
            }
        }
        #pragma unroll
        for (int i = 0; i < 4; ++i) {
            int f = t + 256 * i;
            int nr = f >> 3, c8 = f & 7;
            size_t gsrc = (size_t)nr * K + kc + c8 * 8;
            int byte = nr * 128 + ((c8 * 16) ^ ((nr & 7) << 4));
            *(s16x8*)(cWh + byte) = *(const s16x8*)&Wth[gsrc];
        }
        __syncthreads();
        #pragma unroll
        for (int ks = 0; ks < 2; ++ks) {
            int jA = ks * 4 + (l >> 4);
            int ar = w * 16 + l15;
            int aoff = ar * 128 + ((jA * 16) ^ ((ar & 7) << 4));
            s16x8 fah = *(s16x8*)(cAh + aoff);
            #pragma unroll
            for (int nt = 0; nt < 8; ++nt) {
                int nr = nt * 16 + l15;
                int boff = nr * 128 + ((jA * 16) ^ ((nr & 7) << 4));
                acc[nt] = __builtin_amdgcn_mfma_f32_16x16x32_bf16(fah, *(s16x8*)(cWh + boff), acc[nt], 0, 0, 0);
            }
        }
        __syncthreads();
    }

    const int rbase = row0 + w * 16 + ((l >> 4) << 2);
    #pragma unroll
    for (int nt = 0; nt < 8; ++nt) {
        int col = nt * 16 + l15;
        float bb = bias[col];
        float gm = bng[col], bt = bnb[col], mn = bnm[col], vr = bnv[col];
        #pragma unroll
        for (int r = 0; r < 4; ++r) {
            int row = rbase + r;
            if (row < n) {
                float o = acc[nt][r] + bb;
                o = eluf((o - mn) * rsqrtf(vr + EPS) * gm + bt);
                C16[(size_t)row * HID + col] = f2bf(o);
            }
        }
    }
}

// ---------------------------------------------------------------------------
// Fused per-layer QKVGR, hi-only bf16, double-buffered W staging.
// Carries a CSR chunk (layer 0 only).
// ---------------------------------------------------------------------------
struct QKVGRArgs {
    const unsigned short* wh[5];
    const float* bias[5];
};

__global__ __launch_bounds__(256) void fused_qkvgr(
    const unsigned short* __restrict__ A16, QKVGRArgs ar,
    unsigned short* __restrict__ qb16, unsigned short* __restrict__ kb16,
    unsigned short* __restrict__ vb16,
    unsigned char* __restrict__ gb8, float* __restrict__ accout, int n,
    const int* __restrict__ ei, int* cntp, int* crowp, int Etot, int e0, int e1,
    int hostGrid)
{
    if (csr_side(hostGrid, ei, cntp, crowp, Etot, e0, e1)) return;

    __shared__ char smem[81920];
    char* cA = smem;                                      // 16KB
    char* wb0 = smem + 16384;                             // 32KB
    char* wb1 = smem + 49152;                             // 32KB

    const int t = threadIdx.x;
    const int l = t & 63;
    const int w = t >> 6;
    const int l15 = l & 15;
    const int row0 = blockIdx.x * 64;

    #pragma unroll
    for (int i = 0; i < 4; ++i) {
        int f = t + 256 * i;
        int r = f >> 4, c8 = f & 15;
        int gr = row0 + r; if (gr > n - 1) gr = n - 1;
        int byte = r * 256 + ((c8 * 16) ^ ((r & 7) << 4));
        *(s16x8*)(cA + byte) = *(const s16x8*)&A16[(size_t)gr * HID + c8 * 8];
    }
    __syncthreads();

    s16x8 fah[4];
    {
        const int arow = w * 16 + l15;
        #pragma unroll
        for (int ks = 0; ks < 4; ++ks) {
            int aoff = arow * 256 + (((ks * 64) + (l >> 4) * 16) ^ ((arow & 7) << 4));
            fah[ks] = *(s16x8*)(cA + aoff);
        }
    }
    {
        const unsigned short* wh = ar.wh[0];
        #pragma unroll
        for (int i = 0; i < 8; ++i) {
            int f = t + 256 * i;
            int nr = f >> 4, c8 = f & 15;
            int byte = nr * 256 + ((c8 * 16) ^ ((nr & 7) << 4));
            *(s16x8*)(wb0 + byte) = *(const s16x8*)&wh[(size_t)nr * HID + c8 * 8];
        }
    }
    __syncthreads();

    const int rbase = row0 + w * 16 + ((l >> 4) << 2);

    for (int m = 0; m < 5; ++m) {
        char* cw = (m & 1) ? wb1 : wb0;
        if (m < 4) {
            char* nw = (m & 1) ? wb0 : wb1;
            const unsigned short* wh = ar.wh[m + 1];
            #pragma unroll
            for (int i = 0; i < 8; ++i) {
                int f = t + 256 * i;
                int nr = f >> 4, c8 = f & 15;
                int byte = nr * 256 + ((c8 * 16) ^ ((nr & 7) << 4));
                *(s16x8*)(nw + byte) = *(const s16x8*)&wh[(size_t)nr * HID + c8 * 8];
            }
        }

        f32x4 acc[8] = {};
        #pragma unroll
        for (int ks = 0; ks < 4; ++ks) {
            #pragma unroll
            for (int nt = 0; nt < 8; ++nt) {
                int nr = nt * 16 + l15;
                int boff = nr * 256 + (((ks * 64) + (l >> 4) * 16) ^ ((nr & 7) << 4));
                acc[nt] = __builtin_amdgcn_mfma_f32_16x16x32_bf16(fah[ks], *(s16x8*)(cw + boff), acc[nt], 0, 0, 0);
            }
        }

        float bb[8];
        #pragma unroll
        for (int nt = 0; nt < 8; ++nt) bb[nt] = ar.bias[m][nt * 16 + l15];

        if (m <= 1) {
            unsigned short* out = (m == 0) ? qb16 : kb16;
            #pragma unroll
            for (int r = 0; r < 4; ++r) {
                float ss = 0.f;
                #pragma unroll
                for (int nt = 0; nt < 8; ++nt) {
                    float o = acc[nt][r] + bb[nt];
                    ss += o * o;
                }
                ss += __shfl_xor(ss, 1); ss += __shfl_xor(ss, 2);
                ss += __shfl_xor(ss, 4); ss += __shfl_xor(ss, 8);
                float rn = rsqrtf(ss);
                int row = rbase + r;
                if (row < n) {
                    #pragma unroll
                    for (int nt = 0; nt < 8; ++nt)
                        out[(size_t)row * HID + nt * 16 + l15] = f2bf((acc[nt][r] + bb[nt]) * rn);
                }
            }
        } else if (m == 2) {
            #pragma unroll
            for (int r = 0; r < 4; ++r) {
                int row = rbase + r;
                if (row < n) {
                    #pragma unroll
                    for (int nt = 0; nt < 8; ++nt)
                        vb16[(size_t)row * HID + nt * 16 + l15] = f2bf(acc[nt][r] + bb[nt]);
                }
            }
        } else if (m == 3) {
            #pragma unroll
            for (int r = 0; r < 4; ++r) {
                int row = rbase + r;
                if (row < n) {
                    #pragma unroll
                    for (int nt = 0; nt < 8; ++nt)
                        gb8[(size_t)row * HID + nt * 16 + l15] = f2fp8(acc[nt][r] + bb[nt]);
                }
            }
        } else {
            #pragma unroll
            for (int r = 0; r < 4; ++r) {
                int row = rbase + r;
                if (row < n) {
                    #pragma unroll
                    for (int nt = 0; nt < 8; ++nt) {
                        int col = nt * 16 + l15;
                        accout[(size_t)row * HID + col] =
                            acc[nt][r] + bb[nt] + bf2f(A16[(size_t)row * HID + col]);
                    }
                }
            }
        }
        __syncthreads();
    }
}

// ---------------------------------------------------------------------------
// num+combine: accio += (qn @ kvs + sum_v) / (qn . sum_kn + nf)
// Carries a CSR chunk (layer 0 only).
// ---------------------------------------------------------------------------
__global__ __launch_bounds__(256) void gemm_num_combine(
    const unsigned short* __restrict__ A16,
    const unsigned short* __restrict__ Bth,
    const float* __restrict__ sumv, const float* __restrict__ snk,
    float nf, float* __restrict__ accio, int n,
    const int* __restrict__ ei, int* cntp, int* crowp, int Etot, int e0, int e1,
    int hostGrid)
{
    if (csr_side(hostGrid, ei, cntp, crowp, Etot, e0, e1)) return;

    __shared__ char smem[16384 + 32768];
    char* cA = smem;
    char* cW = smem + 16384;

    const int t = threadIdx.x;
    const int l = t & 63;
    const int w = t >> 6;
    const int l15 = l & 15;
    const int row0 = blockIdx.x * 64;

    #pragma unroll
    for (int i = 0; i < 4; ++i) {
        int f = t + 256 * i;
        int r = f >> 4, c8 = f & 15;
        int gr = row0 + r; if (gr > n - 1) gr = n - 1;
        int byte = r * 256 + ((c8 * 16) ^ ((r & 7) << 4));
        *(s16x8*)(cA + byte) = *(const s16x8*)&A16[(size_t)gr * HID + c8 * 8];
    }
    #pragma unroll
    for (int i = 0; i < 8; ++i) {
        int f = t + 256 * i;
        int nr = f >> 4, c8 = f & 15;
        int byte = nr * 256 + ((c8 * 16) ^ ((nr & 7) << 4));
        *(s16x8*)(cW + byte) = *(const s16x8*)&Bth[(size_t)nr * HID + c8 * 8];
    }
    __syncthreads();

    f32x4 acc[8] = {};
    const int arow = w * 16 + l15;
    #pragma unroll
    for (int ks = 0; ks < 4; ++ks) {
        int aoff = arow * 256 + (((ks * 64) + (l >> 4) * 16) ^ ((arow & 7) << 4));
        s16x8 fa = *(s16x8*)(cA + aoff);
        #pragma unroll
        for (int nt = 0; nt < 8; ++nt) {
            int nr = nt * 16 + l15;
            int boff = nr * 256 + (((ks * 64) + (l >> 4) * 16) ^ ((nr & 7) << 4));
            acc[nt] = __builtin_amdgcn_mfma_f32_16x16x32_bf16(fa, *(s16x8*)(cW + boff), acc[nt], 0, 0, 0);
        }
    }

    const int rbase = row0 + w * 16 + ((l >> 4) << 2);
    float bb[8], skn[8];
    #pragma unroll
    for (int nt = 0; nt < 8; ++nt) {
        bb[nt]  = sumv[nt * 16 + l15];
        skn[nt] = snk[nt * 16 + l15];
    }
    #pragma unroll
    for (int r = 0; r < 4; ++r) {
        int row = rbase + r;
        float p = 0.f;
        if (row < n) {
            #pragma unroll
            for (int nt = 0; nt < 8; ++nt)
                p += bf2f(A16[(size_t)row * HID + nt * 16 + l15]) * skn[nt];
        }
        p += __shfl_xor(p, 1); p += __shfl_xor(p, 2);
        p += __shfl_xor(p, 4); p += __shfl_xor(p, 8);
        float dinv = 1.f / (p + nf);
        if (row < n) {
            #pragma unroll
            for (int nt = 0; nt < 8; ++nt) {
                size_t idx = (size_t)row * HID + nt * 16 + l15;
                accio[idx] += (acc[nt][r] + bb[nt]) * dinv;
            }
        }
    }
}

// ------------------- weight pre-convert (+transpose), hi-only ---------------
struct WConvArgs {
    const float* src[18];
    unsigned short* dh[18];
    int K[18];
};

__global__ void conv_weights(WConvArgs a)
{
    int m = blockIdx.x;
    const float* s = a.src[m];
    unsigned short* dh = a.dh[m];
    int K = a.K[m];
    int tot = 128 * K;
    int slice = (tot + gridDim.y - 1) / gridDim.y;
    int i0 = blockIdx.y * slice;
    int i1 = min(tot, i0 + slice);
    for (int idx = i0 + threadIdx.x; idx < i1; idx += 256) {
        int nn = idx / K, k = idx - nn * K;
        dh[idx] = f2bf(s[(size_t)k * 128 + nn]);
    }
}

// ---------------- kvs stage 1: per-block partial kn^T @ v (bf16 in) ---------
__global__ __launch_bounds__(256) void reduce_kvs_p1(
    const unsigned short* __restrict__ kn, const unsigned short* __restrict__ v,
    int n, int rpb, float* __restrict__ partial)
{
    __shared__ float kl[32][128], vl[32][128];
    const int t  = threadIdx.x;
    const int tx = t & 15;
    const int ty = t >> 4;
    const int r0 = blockIdx.x * rpb;
    const int r1 = min(n, r0 + rpb);

    float acc[8][8] = {};
    float sk[8] = {}, sv[8] = {};

    for (int base = r0; base < r1; base += 32) {
        float4 kz[4], vz[4];
        #pragma unroll
        for (int i = 0; i < 4; ++i) {
            int f = t + 256 * i;
            int rr = f >> 5, c4 = f & 31;
            int gr = base + rr;
            if (gr < r1) {
                us16x4 ku = *(const us16x4*)&kn[(size_t)gr * HID + c4 * 4];
                us16x4 vu = *(const us16x4*)&v [(size_t)gr * HID + c4 * 4];
                kz[i] = make_float4(bf2f(ku[0]), bf2f(ku[1]), bf2f(ku[2]), bf2f(ku[3]));
                vz[i] = make_float4(bf2f(vu[0]), bf2f(vu[1]), bf2f(vu[2]), bf2f(vu[3]));
            } else {
                kz[i] = make_float4(0, 0, 0, 0);
                vz[i] = make_float4(0, 0, 0, 0);
            }
        }
        __syncthreads();
        #pragma unroll
        for (int i = 0; i < 4; ++i) {
            int f = t + 256 * i;
            int rr = f >> 5, c4 = f & 31;
            *(float4*)&kl[rr][c4 * 4] = kz[i];
            *(float4*)&vl[rr][c4 * 4] = vz[i];
        }
        __syncthreads();
        #pragma unroll 8
        for (int rr = 0; rr < 32; ++rr) {
            float kk[8], vv[8];
            *(float4*)&kk[0] = *(float4*)&kl[rr][ty * 4];
            *(float4*)&kk[4] = *(float4*)&kl[rr][64 + ty * 4];
            *(float4*)&vv[0] = *(float4*)&vl[rr][tx * 4];
            *(float4*)&vv[4] = *(float4*)&vl[rr][64 + tx * 4];
            #pragma unroll
            for (int i = 0; i < 8; ++i)
                #pragma unroll
                for (int j = 0; j < 8; ++j)
                    acc[i][j] += kk[i] * vv[j];
            if (tx == 0) {
                #pragma unroll
                for (int i = 0; i < 8; ++i) sk[i] += kk[i];
            }
            if (ty == 0) {
                #pragma unroll
                for (int j = 0; j < 8; ++j) sv[j] += vv[j];
            }
        }
        __syncthreads();
    }

    float* pb = partial + (size_t)blockIdx.x * 16640;
    #pragma unroll
    for (int i = 0; i < 8; ++i) {
        int kd = (i < 4) ? (ty * 4 + i) : (64 + ty * 4 + i - 4);
        *(float4*)&pb[kd * HID + tx * 4]      = make_float4(acc[i][0], acc[i][1], acc[i][2], acc[i][3]);
        *(float4*)&pb[kd * HID + 64 + tx * 4] = make_float4(acc[i][4], acc[i][5], acc[i][6], acc[i][7]);
    }
    if (tx == 0) {
        #pragma unroll
        for (int i = 0; i < 8; ++i) {
            int kd = (i < 4) ? (ty * 4 + i) : (64 + ty * 4 + i - 4);
            pb[16384 + kd] = sk[i];
        }
    }
    if (ty == 0) {
        #pragma unroll
        for (int j = 0; j < 8; ++j) {
            int vd = (j < 4) ? (tx * 4 + j) : (64 + tx * 4 + j - 4);
            pb[16512 + vd] = sv[j];
        }
    }
}

// ------- kvs stage 2: sum partials -> bf16 transposed kvs (hi) + sums -------
__global__ __launch_bounds__(256) void reduce_kvs_p2(
    const float* __restrict__ partial, int nb,
    unsigned short* __restrict__ kvth, float* __restrict__ sums)
{
    __shared__ float lds[256];
    const int t    = threadIdx.x;
    const int o    = blockIdx.x * 64 + (t & 63);
    const int part = t >> 6;
    const int per  = (nb + 3) >> 2;
    const int b0   = part * per;
    const int b1   = min(nb, b0 + per);
    float s = 0.f;
    for (int b = b0; b < b1; ++b)
        s += partial[(size_t)b * 16640 + o];
    lds[t] = s;
    __syncthreads();
    if (part == 0) {
        float tot = lds[t] + lds[t + 64] + lds[t + 128] + lds[t + 192];
        if (o < 16384) {
            int k = o >> 7, nn = o & 127;
            kvth[nn * 128 + k] = f2bf(tot);
        } else {
            sums[o - 16384] = tot;
        }
    }
}

__global__ void rdeg_k(const int* __restrict__ cur, float* __restrict__ rdeg, int n)
{
    int i = blockIdx.x * 256 + threadIdx.x;
    if (i < n) {
        int c = cur[i];
        rdeg[i] = (c > 0) ? rsqrtf((float)c) : 0.f;
    }
}

// --------- fused gather + LN + ELU: 2 nodes/wave, dword fp8 loads -----------
__global__ __launch_bounds__(256) void gather_ln_elu2(
    const int* __restrict__ cnt, const int* __restrict__ crow,
    const float* __restrict__ rdeg,
    const unsigned char* __restrict__ g, const float* __restrict__ accin,
    const float* __restrict__ gam, const float* __restrict__ bet,
    float* __restrict__ outf, unsigned short* __restrict__ out16, int n)
{
    int wid  = (int)((blockIdx.x * 256 + threadIdx.x) >> 6);
    int half = (threadIdx.x >> 5) & 1;
    int li   = threadIdx.x & 31;
    int node = wid * 2 + half;
    if (node >= n) return;

    int cn = cnt[node]; if (cn > SLOTS) cn = SLOTS;
    const int* cr = &crow[(size_t)node * SLOTS];
    float rd = rdeg[node];
    float4 a = *(const float4*)&accin[(size_t)node * HID + li * 4];

    int i = 0;
    for (; i + 3 < cn; i += 4) {
        int   r0 = cr[i],     r1 = cr[i + 1];
        int   r2 = cr[i + 2], r3 = cr[i + 3];
        float w0 = rd * rdeg[r0], w1 = rd * rdeg[r1];
        float w2 = rd * rdeg[r2], w3 = rd * rdeg[r3];
        unsigned u0 = *(const unsigned*)&g[(size_t)r0 * HID + li * 4];
        unsigned u1 = *(const unsigned*)&g[(size_t)r1 * HID + li * 4];
        unsigned u2 = *(const unsigned*)&g[(size_t)r2 * HID + li * 4];
        unsigned u3 = *(const unsigned*)&g[(size_t)r3 * HID + li * 4];
        f32x2 p0l = __builtin_amdgcn_cvt_pk_f32_fp8((int)u0, false);
        f32x2 p0h = __builtin_amdgcn_cvt_pk_f32_fp8((int)u0, true);
        f32x2 p1l = __builtin_amdgcn_cvt_pk_f32_fp8((int)u1, false);
        f32x2 p1h = __builtin_amdgcn_cvt_pk_f32_fp8((int)u1, true);
        f32x2 p2l = __builtin_amdgcn_cvt_pk_f32_fp8((int)u2, false);
        f32x2 p2h = __builtin_amdgcn_cvt_pk_f32_fp8((int)u2, true);
        f32x2 p3l = __builtin_amdgcn_cvt_pk_f32_fp8((int)u3, false);
        f32x2 p3h = __builtin_amdgcn_cvt_pk_f32_fp8((int)u3, true);
        a.x += w0 * p0l[0] + w1 * p1l[0] + w2 * p2l[0] + w3 * p3l[0];
        a.y += w0 * p0l[1] + w1 * p1l[1] + w2 * p2l[1] + w3 * p3l[1];
        a.z += w0 * p0h[0] + w1 * p1h[0] + w2 * p2h[0] + w3 * p3h[0];
        a.w += w0 * p0h[1] + w1 * p1h[1] + w2 * p2h[1] + w3 * p3h[1];
    }
    for (; i < cn; ++i) {
        int r0 = cr[i];
        float w0 = rd * rdeg[r0];
        unsigned u0 = *(const unsigned*)&g[(size_t)r0 * HID + li * 4];
        f32x2 p0l = __builtin_amdgcn_cvt_pk_f32_fp8((int)u0, false);
        f32x2 p0h = __builtin_amdgcn_cvt_pk_f32_fp8((int)u0, true);
        a.x += w0 * p0l[0]; a.y += w0 * p0l[1];
        a.z += w0 * p0h[0]; a.w += w0 * p0h[1];
    }

    float sm = a.x + a.y + a.z + a.w;
    float ss = a.x * a.x + a.y * a.y + a.z * a.z + a.w * a.w;
    #pragma unroll
    for (int o = 16; o; o >>= 1) { sm += __shfl_xor(sm, o); ss += __shfl_xor(ss, o); }
    float mu  = sm * (1.f / 128.f);
    float var = ss * (1.f / 128.f) - mu * mu;
    float rs  = rsqrtf(var + EPS);
    float4 gm = *(const float4*)&gam[li * 4];
    float4 bt = *(const float4*)&bet[li * 4];
    float y0 = eluf((a.x - mu) * rs * gm.x + bt.x);
    float y1 = eluf((a.y - mu) * rs * gm.y + bt.y);
    float y2 = eluf((a.z - mu) * rs * gm.z + bt.z);
    float y3 = eluf((a.w - mu) * rs * gm.w + bt.w);
    if (out16) {
        us16x4 o4 = (us16x4){f2bf(y0), f2bf(y1), f2bf(y2), f2bf(y3)};
        *(us16x4*)&out16[(size_t)node * HID + li * 4] = o4;
    } else {
        *(float4*)&outf[(size_t)node * HID + li * 4] = make_float4(y0, y1, y2, y3);
    }
}

// ---------------------------------------------------------------------------
extern "C" void kernel_launch(void* const* d_in, const int* in_sizes, int n_in,
                              void* d_out, int out_size, void* d_ws, size_t ws_size,
                              hipStream_t stream)
{
    const float* x      = (const float*)d_in[0];
    const int*   ei     = (const int*)  d_in[1];
    const float* mlp_W0 = (const float*)d_in[2];
    const float* mlp_b0 = (const float*)d_in[3];
    const float* mlp_W  = (const float*)d_in[4];
    const float* mlp_b  = (const float*)d_in[5];
    const float* bn_g   = (const float*)d_in[6];
    const float* bn_b   = (const float*)d_in[7];
    const float* bn_m   = (const float*)d_in[8];
    const float* bn_v   = (const float*)d_in[9];
    const float* Wq = (const float*)d_in[10]; const float* bq = (const float*)d_in[11];
    const float* Wk = (const float*)d_in[12]; const float* bk = (const float*)d_in[13];
    const float* Wv = (const float*)d_in[14]; const float* bv = (const float*)d_in[15];
    const float* Wg = (const float*)d_in[16]; const float* bg = (const float*)d_in[17];
    const float* Wr = (const float*)d_in[18]; const float* br = (const float*)d_in[19];
    const float* ln_g = (const float*)d_in[20];
    const float* ln_b = (const float*)d_in[21];

    const int N = in_sizes[0] / INC;
    const int E = in_sizes[1] / 2;
    const size_t P = (size_t)N * HID;

    // workspace layout
    float* ws   = (float*)d_ws;
    float* part = ws;                        // P f32 (kvs partials)
    unsigned short* h16  = (unsigned short*)(part + P);   // P bf16
    unsigned short* qb16 = h16 + P;                       // P bf16
    unsigned short* kb16 = qb16 + P;                      // P bf16 (also MLP scratch A)
    unsigned short* vb16 = kb16 + P;                      // P bf16 (also MLP scratch B)
    unsigned char*  gb8  = (unsigned char*)(vb16 + P);    // P fp8
    float* kvs  = (float*)(gb8 + P);         // 256 floats: [sum_kn][sum_v]
    int*   crow = (int*)(kvs + 256);         // N*SLOTS
    int*   cnt  = crow + (size_t)N * SLOTS;  // N
    float* rdeg = (float*)(cnt + N);         // N
    unsigned short* wt = (unsigned short*)(rdeg + N);

    unsigned short* WTh[18];
    int Ks[18];
    size_t woff = 0;
    for (int m = 0; m < 18; ++m) {
        int K = (m == 0) ? INC : HID;
        Ks[m] = K;
        WTh[m] = wt + woff;           woff += (size_t)128 * K;
    }
    unsigned short* kvth = wt + woff; woff += 16384;
    float* acc = (float*)d_out;

    int nbk = NB_KVS;
    if ((size_t)nbk * 16640 > P) nbk = (int)(P / 16640);
    const int rpb = (N + nbk - 1) / nbk;

    const int gemmGrid = (N + 63) / 64;
    const int gw2Grid  = (N + 7) / 8;
    const int nodeGrid = (N + 255) / 256;

    // CSR chunk bounds: 5 chunks hidden under MLP0/1/2, qkvgr0, num_combine0
    int eb[6];
    for (int i = 0; i <= 5; ++i) eb[i] = (int)(((long long)E * i) / 5);
    auto cb = [&](int i) { return (eb[i + 1] - eb[i] + 255) / 256; };

    // --- weight pre-convert (hi-only, transposed) ---
    WConvArgs wa;
    const float* srcs[18];
    srcs[0] = mlp_W0; srcs[1] = mlp_W; srcs[2] = mlp_W + (size_t)HID * HID;
    for (int l = 0; l < NLAYER; ++l) {
        const size_t wo = (size_t)l * HID * HID;
        srcs[3 + l * 5 + 0] = Wq + wo;
        srcs[3 + l * 5 + 1] = Wk + wo;
        srcs[3 + l * 5 + 2] = Wv + wo;
        srcs[3 + l * 5 + 3] = Wg + wo;
        srcs[3 + l * 5 + 4] = Wr + wo;
    }
    for (int m = 0; m < 18; ++m) {
        wa.src[m] = srcs[m]; wa.dh[m] = WTh[m]; wa.K[m] = Ks[m];
    }
    conv_weights<<<dim3(18, 8), 256, 0, stream>>>(wa);

    hipMemsetAsync(cnt, 0, (size_t)N * sizeof(int), stream);

    // --- MLP (each hosts a CSR chunk) ---
    gemm_mlp<INC, true><<<gemmGrid + cb(0), 256, 0, stream>>>(x, nullptr, WTh[0], mlp_b0,
        bn_g, bn_b, bn_m, bn_v, kb16, N, ei, cnt, crow, E, eb[0], eb[1], gemmGrid);
    gemm_mlp<HID, false><<<gemmGrid + cb(1), 256, 0, stream>>>(nullptr, kb16, WTh[1], mlp_b,
        bn_g + HID, bn_b + HID, bn_m + HID, bn_v + HID, vb16, N,
        ei, cnt, crow, E, eb[1], eb[2], gemmGrid);
    gemm_mlp<HID, false><<<gemmGrid + cb(2), 256, 0, stream>>>(nullptr, vb16, WTh[2], mlp_b + HID,
        bn_g + 2 * HID, bn_b + 2 * HID, bn_m + 2 * HID, bn_v + 2 * HID, h16, N,
        ei, cnt, crow, E, eb[2], eb[3], gemmGrid);

    // --- TransConv layers ---
    for (int l = 0; l < NLAYER; ++l) {
        const int bo = l * HID;
        const bool l0 = (l == 0);

        QKVGRArgs qa;
        for (int m = 0; m < 5; ++m) qa.wh[m] = WTh[3 + l * 5 + m];
        qa.bias[0] = bq + bo; qa.bias[1] = bk + bo; qa.bias[2] = bv + bo;
        qa.bias[3] = bg + bo; qa.bias[4] = br + bo;

        // h16 -> qn, kn, v, g, acc  (layer 0 hosts CSR chunk 3)
        fused_qkvgr<<<gemmGrid + (l0 ? cb(3) : 0), 256, 0, stream>>>(h16, qa,
            qb16, kb16, vb16, gb8, acc, N,
            ei, cnt, crow, E, l0 ? eb[3] : 0, l0 ? eb[4] : 0, gemmGrid);

        // kvs = kn^T @ v
        reduce_kvs_p1<<<nbk, 256, 0, stream>>>(kb16, vb16, N, rpb, part);
        reduce_kvs_p2<<<260, 256, 0, stream>>>(part, nbk, kvth, kvs);

        // acc += (qn @ kvs + sum_v) / (qn . sum_kn + N)  (layer 0 hosts chunk 4)
        gemm_num_combine<<<gemmGrid + (l0 ? cb(4) : 0), 256, 0, stream>>>(qb16, kvth,
            kvs + 128, kvs, (float)N, acc, N,
            ei, cnt, crow, E, l0 ? eb[4] : 0, l0 ? eb[5] : 0, gemmGrid);

        // rdeg after the last CSR chunk, before the first gather
        if (l0) rdeg_k<<<nodeGrid, 256, 0, stream>>>(cnt, rdeg, N);

        // fused gather (fp8 g, 2 nodes/wave) + LN + ELU
        bool last = (l == NLAYER - 1);
        gather_ln_elu2<<<gw2Grid, 256, 0, stream>>>(cnt, crow, rdeg,
            gb8, acc, ln_g + bo, ln_b + bo,
            last ? acc : nullptr, last ? nullptr : h16, N);
    }
}

// Round 12
// 1060.503 us; speedup vs baseline: 1.3261x; 1.0320x over previous
//
#include <hip/hip_runtime.h>
#include <cstdint>
#include <cstddef>

#define HID 128
#define INC 256
#define NLAYER 3
#define SLOTS 96

static constexpr float EPS = 1e-5f;

typedef __attribute__((ext_vector_type(8))) short s16x8;
typedef __attribute__((ext_vector_type(4))) unsigned short us16x4;
typedef __attribute__((ext_vector_type(4))) float f32x4;
typedef __attribute__((ext_vector_type(2))) float f32x2;

__device__ __forceinline__ float eluf(float x) { return x > 0.f ? x : expm1f(x); }

__device__ __forceinline__ unsigned short f2bf(float x)
{
    unsigned u = __float_as_uint(x);
    u += 0x7FFFu + ((u >> 16) & 1u);
    return (unsigned short)(u >> 16);
}

__device__ __forceinline__ float bf2f(unsigned short u)
{
    return __uint_as_float(((unsigned)u) << 16);
}

__device__ __forceinline__ unsigned char f2fp8(float x)
{
    return (unsigned char)(__builtin_amdgcn_cvt_pk_fp8_f32(x, x, 0, false) & 0xFF);
}

// ---- CSR co-run side-job: blocks past hostGrid fill an edge range ----------
__device__ __forceinline__ bool csr_side(int hostGrid, const int* __restrict__ ei,
                                         int* cnt, int* crow, int Etot, int e0, int e1)
{
    if ((int)blockIdx.x < hostGrid) return false;
    int e = e0 + (int)(blockIdx.x - hostGrid) * 256 + (int)threadIdx.x;
    if (e < e1) {
        int r = ei[e], c = ei[Etot + e];
        int p = atomicAdd(&cnt[c], 1);
        if (p < SLOTS) crow[(size_t)c * SLOTS + p] = r;
    }
    return true;
}

// ---------------------------------------------------------------------------
// MLP GEMM, hi-only bf16: C16 = bf16(ELU(BN(A[n,K] @ W + bias))).
// ---------------------------------------------------------------------------
template<int K, bool IN32>
__global__ __launch_bounds__(256) void gemm_mlp(
    const float* __restrict__ Af, const unsigned short* __restrict__ A16,
    const unsigned short* __restrict__ Wth,
    const float* __restrict__ bias,
    const float* __restrict__ bng, const float* __restrict__ bnb,
    const float* __restrict__ bnm, const float* __restrict__ bnv,
    unsigned short* __restrict__ C16, int n,
    const int* __restrict__ ei, int* cntp, int* crowp, int Etot, int e0, int e1,
    int hostGrid)
{
    if (csr_side(hostGrid, ei, cntp, crowp, Etot, e0, e1)) return;

    __shared__ unsigned short Ah[64 * 64], Wh[128 * 64];
    const int t = threadIdx.x;
    const int l = t & 63;
    const int w = t >> 6;
    const int l15 = l & 15;
    const int row0 = blockIdx.x * 64;

    char* cAh = (char*)Ah;
    char* cWh = (char*)Wh;

    f32x4 acc[8] = {};

    for (int kc = 0; kc < K; kc += 64) {
        if (IN32) {
            #pragma unroll
            for (int i = 0; i < 4; ++i) {
                int f = t + 256 * i;
                int r = f >> 4, c4 = f & 15;
                int gr = row0 + r; if (gr > n - 1) gr = n - 1;
                float4 a4 = *(const float4*)&Af[(size_t)gr * K + kc + c4 * 4];
                int byte = r * 128 + (((c4 >> 1) * 16) ^ ((r & 7) << 4)) + (c4 & 1) * 8;
                *(us16x4*)(cAh + byte) =
                    (us16x4){f2bf(a4.x), f2bf(a4.y), f2bf(a4.z), f2bf(a4.w)};
            }
        } else {
            #pragma unroll
            for (int i = 0; i < 2; ++i) {
                int f = t + 256 * i;
                int r = f >> 3, c8 = f & 7;
                int gr = row0 + r; if (gr > n - 1) gr = n - 1;
                int byte = r * 128 + ((c8 * 16) ^ ((r & 7) << 4));
                *(s16x8*)(cAh + byte) = *(const s16x8*)&A16[(size_t)gr * K + kc + c8 * 8];
            }
        }
        #pragma unroll
        for (int i = 0; i < 4; ++i) {
            int f = t + 256 * i;
            int nr = f >> 3, c8 = f & 7;
            size_t gsrc = (size_t)nr * K + kc + c8 * 8;
            int byte = nr * 128 + ((c8 * 16) ^ ((nr & 7) << 4));
            *(s16x8*)(cWh + byte) = *(const s16x8*)&Wth[gsrc];
        }
        __syncthreads();
        #pragma unroll
        for (int ks = 0; ks < 2; ++ks) {
            int jA = ks * 4 + (l >> 4);
            int ar = w * 16 + l15;
            int aoff = ar * 128 + ((jA * 16) ^ ((ar & 7) << 4));
            s16x8 fah = *(s16x8*)(cAh + aoff);
            #pragma unroll
            for (int nt = 0; nt < 8; ++nt) {
                int nr = nt * 16 + l15;
                int boff = nr * 128 + ((jA * 16) ^ ((nr & 7) << 4));
                acc[nt] = __builtin_amdgcn_mfma_f32_16x16x32_bf16(fah, *(s16x8*)(cWh + boff), acc[nt], 0, 0, 0);
            }
        }
        __syncthreads();
    }

    const int rbase = row0 + w * 16 + ((l >> 4) << 2);
    #pragma unroll
    for (int nt = 0; nt < 8; ++nt) {
        int col = nt * 16 + l15;
        float bb = bias[col];
        float gm = bng[col], bt = bnb[col], mn = bnm[col], vr = bnv[col];
        #pragma unroll
        for (int r = 0; r < 4; ++r) {
            int row = rbase + r;
            if (row < n) {
                float o = acc[nt][r] + bb;
                o = eluf((o - mn) * rsqrtf(vr + EPS) * gm + bt);
                C16[(size_t)row * HID + col] = f2bf(o);
            }
        }
    }
}

// ---------------------------------------------------------------------------
// Fused per-layer QKVGR + kvs: hi-only bf16, W single-buffered.
// LDS: [A/knT 16KB][W 32KB][vT 16KB] = 64KB -> 2 blocks/CU.
//   m=0 q: +bias, L2-norm -> qb16       m=1 k: +bias, L2-norm -> knT (LDS)
//   m=2 v: +bias -> vT (LDS)            m=3 g: +bias -> gb8 (fp8)
//   m=4 r: +bias + h(res) -> acc (f32)
// tail: partial kvs via 32 MFMA (M=N=128, K=64) + row sums -> partial (bf16)
// ---------------------------------------------------------------------------
struct QKVGRArgs {
    const unsigned short* wh[5];
    const float* bias[5];
};

__global__ __launch_bounds__(256) void fused_qkvgr(
    const unsigned short* __restrict__ A16, QKVGRArgs ar,
    unsigned short* __restrict__ qb16,
    unsigned char* __restrict__ gb8, float* __restrict__ accout,
    unsigned short* __restrict__ partial, int n,
    const int* __restrict__ ei, int* cntp, int* crowp, int Etot, int e0, int e1,
    int hostGrid)
{
    if (csr_side(hostGrid, ei, cntp, crowp, Etot, e0, e1)) return;

    __shared__ char smem[65536];
    char* cA  = smem;             // 16KB: staged h; becomes knT after m=1
    char* cW  = smem + 16384;     // 32KB: W (single-buffered)
    char* cVT = smem + 49152;     // 16KB: vT

    const int t = threadIdx.x;
    const int l = t & 63;
    const int w = t >> 6;
    const int l15 = l & 15;
    const int row0 = blockIdx.x * 64;

    // ---- stage A (bf16, swizzled, row stride 256B) ----
    #pragma unroll
    for (int i = 0; i < 4; ++i) {
        int f = t + 256 * i;
        int r = f >> 4, c8 = f & 15;
        int gr = row0 + r; if (gr > n - 1) gr = n - 1;
        int byte = r * 256 + ((c8 * 16) ^ ((r & 7) << 4));
        *(s16x8*)(cA + byte) = *(const s16x8*)&A16[(size_t)gr * HID + c8 * 8];
    }
    __syncthreads();

    s16x8 fah[4];
    {
        const int arow = w * 16 + l15;
        #pragma unroll
        for (int ks = 0; ks < 4; ++ks) {
            int aoff = arow * 256 + (((ks * 64) + (l >> 4) * 16) ^ ((arow & 7) << 4));
            fah[ks] = *(s16x8*)(cA + aoff);
        }
    }
    __syncthreads();   // all frags loaded before cA is reused at m=1

    const int rbase = row0 + w * 16 + ((l >> 4) << 2);
    const int rtb   = w * 16 + ((l >> 4) << 2);       // row within tile

    for (int m = 0; m < 5; ++m) {
        // ---- stage Wm ----
        {
            const unsigned short* wh = ar.wh[m];
            #pragma unroll
            for (int i = 0; i < 8; ++i) {
                int f = t + 256 * i;
                int nr = f >> 4, c8 = f & 15;
                int byte = nr * 256 + ((c8 * 16) ^ ((nr & 7) << 4));
                *(s16x8*)(cW + byte) = *(const s16x8*)&wh[(size_t)nr * HID + c8 * 8];
            }
        }
        __syncthreads();

        f32x4 acc[8] = {};
        #pragma unroll
        for (int ks = 0; ks < 4; ++ks) {
            #pragma unroll
            for (int nt = 0; nt < 8; ++nt) {
                int nr = nt * 16 + l15;
                int boff = nr * 256 + (((ks * 64) + (l >> 4) * 16) ^ ((nr & 7) << 4));
                acc[nt] = __builtin_amdgcn_mfma_f32_16x16x32_bf16(fah[ks], *(s16x8*)(cW + boff), acc[nt], 0, 0, 0);
            }
        }

        float bb[8];
        #pragma unroll
        for (int nt = 0; nt < 8; ++nt) bb[nt] = ar.bias[m][nt * 16 + l15];

        if (m <= 1) {                       // q / k: bias + row L2 normalize
            #pragma unroll
            for (int r = 0; r < 4; ++r) {
                float ss = 0.f;
                #pragma unroll
                for (int nt = 0; nt < 8; ++nt) {
                    float o = acc[nt][r] + bb[nt];
                    ss += o * o;
                }
                ss += __shfl_xor(ss, 1); ss += __shfl_xor(ss, 2);
                ss += __shfl_xor(ss, 4); ss += __shfl_xor(ss, 8);
                float rn = rsqrtf(ss);
                int row = rbase + r;
                if (m == 0) {
                    if (row < n) {
                        #pragma unroll
                        for (int nt = 0; nt < 8; ++nt)
                            qb16[(size_t)row * HID + nt * 16 + l15] = f2bf((acc[nt][r] + bb[nt]) * rn);
                    }
                } else {
                    // kn -> knT LDS tile [kd=128][r=64] bf16, swizzled, zero-pad
                    int rt = rtb + r;
                    #pragma unroll
                    for (int nt = 0; nt < 8; ++nt) {
                        int kd = nt * 16 + l15;
                        unsigned short v16 = (row < n) ? f2bf((acc[nt][r] + bb[nt]) * rn) : (unsigned short)0;
                        int byte = kd * 128 + ((2 * rt) ^ ((kd & 7) << 4));
                        *(unsigned short*)(cA + byte) = v16;
                    }
                }
            }
        } else if (m == 2) {                // v -> vT LDS tile, zero-pad
            #pragma unroll
            for (int r = 0; r < 4; ++r) {
                int row = rbase + r;
                int rt = rtb + r;
                #pragma unroll
                for (int nt = 0; nt < 8; ++nt) {
                    int vd = nt * 16 + l15;
                    unsigned short v16 = (row < n) ? f2bf(acc[nt][r] + bb[nt]) : (unsigned short)0;
                    int byte = vd * 128 + ((2 * rt) ^ ((vd & 7) << 4));
                    *(unsigned short*)(cVT + byte) = v16;
                }
            }
        } else if (m == 3) {                // g: bias, fp8 store
            #pragma unroll
            for (int r = 0; r < 4; ++r) {
                int row = rbase + r;
                if (row < n) {
                    #pragma unroll
                    for (int nt = 0; nt < 8; ++nt)
                        gb8[(size_t)row * HID + nt * 16 + l15] = f2fp8(acc[nt][r] + bb[nt]);
                }
            }
        } else {                            // r: bias + residual(h)
            #pragma unroll
            for (int r = 0; r < 4; ++r) {
                int row = rbase + r;
                if (row < n) {
                    #pragma unroll
                    for (int nt = 0; nt < 8; ++nt) {
                        int col = nt * 16 + l15;
                        accout[(size_t)row * HID + col] =
                            acc[nt][r] + bb[nt] + bf2f(A16[(size_t)row * HID + col]);
                    }
                }
            }
        }
        __syncthreads();
    }

    // ---- tail: partial kvs[kd][vd] = sum_r knT[kd][r] * vT[vd][r], K=64 ----
    f32x4 kacc[2][8] = {};
    #pragma unroll
    for (int ks = 0; ks < 2; ++ks) {
        #pragma unroll
        for (int mt = 0; mt < 2; ++mt) {
            int kd = w * 32 + mt * 16 + l15;
            int aoff = kd * 128 + ((ks * 64 + (l >> 4) * 16) ^ ((kd & 7) << 4));
            s16x8 fa = *(s16x8*)(cA + aoff);
            #pragma unroll
            for (int nt = 0; nt < 8; ++nt) {
                int vd = nt * 16 + l15;
                int boff = vd * 128 + ((ks * 64 + (l >> 4) * 16) ^ ((vd & 7) << 4));
                kacc[mt][nt] = __builtin_amdgcn_mfma_f32_16x16x32_bf16(fa, *(s16x8*)(cVT + boff), kacc[mt][nt], 0, 0, 0);
            }
        }
    }
    unsigned short* pb = partial + (size_t)blockIdx.x * 16640;
    #pragma unroll
    for (int mt = 0; mt < 2; ++mt) {
        #pragma unroll
        for (int nt = 0; nt < 8; ++nt) {
            #pragma unroll
            for (int r = 0; r < 4; ++r) {
                int kd = w * 32 + mt * 16 + ((l >> 4) << 2) + r;
                pb[kd * 128 + nt * 16 + l15] = f2bf(kacc[mt][nt][r]);
            }
        }
    }
    // row sums: threads 0..127 -> sum_kn[kd]; 128..255 -> sum_v[vd]
    {
        float s = 0.f;
        if (t < 128) {
            #pragma unroll 8
            for (int r = 0; r < 64; ++r) {
                int byte = t * 128 + ((2 * r) ^ ((t & 7) << 4));
                s += bf2f(*(unsigned short*)(cA + byte));
            }
            pb[16384 + t] = f2bf(s);
        } else {
            int vd = t - 128;
            #pragma unroll 8
            for (int r = 0; r < 64; ++r) {
                int byte = vd * 128 + ((2 * r) ^ ((vd & 7) << 4));
                s += bf2f(*(unsigned short*)(cVT + byte));
            }
            pb[16512 + vd] = f2bf(s);
        }
    }
}

// ---------------------------------------------------------------------------
// num+combine: accio += (qn @ kvs + sum_v) / (qn . sum_kn + nf)
// denom reads qn from the LDS stage (no global re-read).
// ---------------------------------------------------------------------------
__global__ __launch_bounds__(256) void gemm_num_combine(
    const unsigned short* __restrict__ A16,
    const unsigned short* __restrict__ Bth,
    const float* __restrict__ sumv, const float* __restrict__ snk,
    float nf, float* __restrict__ accio, int n,
    const int* __restrict__ ei, int* cntp, int* crowp, int Etot, int e0, int e1,
    int hostGrid)
{
    if (csr_side(hostGrid, ei, cntp, crowp, Etot, e0, e1)) return;

    __shared__ char smem[16384 + 32768];
    char* cA = smem;
    char* cW = smem + 16384;

    const int t = threadIdx.x;
    const int l = t & 63;
    const int w = t >> 6;
    const int l15 = l & 15;
    const int row0 = blockIdx.x * 64;

    #pragma unroll
    for (int i = 0; i < 4; ++i) {
        int f = t + 256 * i;
        int r = f >> 4, c8 = f & 15;
        int gr = row0 + r; if (gr > n - 1) gr = n - 1;
        int byte = r * 256 + ((c8 * 16) ^ ((r & 7) << 4));
        *(s16x8*)(cA + byte) = *(const s16x8*)&A16[(size_t)gr * HID + c8 * 8];
    }
    #pragma unroll
    for (int i = 0; i < 8; ++i) {
        int f = t + 256 * i;
        int nr = f >> 4, c8 = f & 15;
        int byte = nr * 256 + ((c8 * 16) ^ ((nr & 7) << 4));
        *(s16x8*)(cW + byte) = *(const s16x8*)&Bth[(size_t)nr * HID + c8 * 8];
    }
    __syncthreads();

    f32x4 acc[8] = {};
    const int arow = w * 16 + l15;
    #pragma unroll
    for (int ks = 0; ks < 4; ++ks) {
        int aoff = arow * 256 + (((ks * 64) + (l >> 4) * 16) ^ ((arow & 7) << 4));
        s16x8 fa = *(s16x8*)(cA + aoff);
        #pragma unroll
        for (int nt = 0; nt < 8; ++nt) {
            int nr = nt * 16 + l15;
            int boff = nr * 256 + (((ks * 64) + (l >> 4) * 16) ^ ((nr & 7) << 4));
            acc[nt] = __builtin_amdgcn_mfma_f32_16x16x32_bf16(fa, *(s16x8*)(cW + boff), acc[nt], 0, 0, 0);
        }
    }

    const int rbase = row0 + w * 16 + ((l >> 4) << 2);
    const int rtb   = w * 16 + ((l >> 4) << 2);
    float bb[8], skn[8];
    #pragma unroll
    for (int nt = 0; nt < 8; ++nt) {
        bb[nt]  = sumv[nt * 16 + l15];
        skn[nt] = snk[nt * 16 + l15];
    }
    #pragma unroll
    for (int r = 0; r < 4; ++r) {
        int row = rbase + r;
        int rt = rtb + r;
        float p = 0.f;
        #pragma unroll
        for (int nt = 0; nt < 8; ++nt) {
            int byte = rt * 256 + ((2 * (nt * 16 + l15)) ^ ((rt & 7) << 4));
            p += bf2f(*(unsigned short*)(cA + byte)) * skn[nt];
        }
        p += __shfl_xor(p, 1); p += __shfl_xor(p, 2);
        p += __shfl_xor(p, 4); p += __shfl_xor(p, 8);
        float dinv = 1.f / (p + nf);
        if (row < n) {
            #pragma unroll
            for (int nt = 0; nt < 8; ++nt) {
                size_t idx = (size_t)row * HID + nt * 16 + l15;
                accio[idx] += (acc[nt][r] + bb[nt]) * dinv;
            }
        }
    }
}

// ------------------- weight pre-convert (+transpose), hi-only ---------------
struct WConvArgs {
    const float* src[18];
    unsigned short* dh[18];
    int K[18];
};

__global__ void conv_weights(WConvArgs a)
{
    int m = blockIdx.x;
    const float* s = a.src[m];
    unsigned short* dh = a.dh[m];
    int K = a.K[m];
    int tot = 128 * K;
    int slice = (tot + gridDim.y - 1) / gridDim.y;
    int i0 = blockIdx.y * slice;
    int i1 = min(tot, i0 + slice);
    for (int idx = i0 + threadIdx.x; idx < i1; idx += 256) {
        int nn = idx / K, k = idx - nn * K;
        dh[idx] = f2bf(s[(size_t)k * 128 + nn]);
    }
}

// ------- kvs stage 2: sum bf16 partials -> bf16 transposed kvs + sums -------
__global__ __launch_bounds__(256) void reduce_kvs_p2(
    const unsigned short* __restrict__ partial, int nb,
    unsigned short* __restrict__ kvth, float* __restrict__ sums)
{
    __shared__ float lds[256];
    const int t    = threadIdx.x;
    const int o    = blockIdx.x * 64 + (t & 63);
    const int part = t >> 6;
    const int per  = (nb + 3) >> 2;
    const int b0   = part * per;
    const int b1   = min(nb, b0 + per);
    float s = 0.f;
    for (int b = b0; b < b1; ++b)
        s += bf2f(partial[(size_t)b * 16640 + o]);
    lds[t] = s;
    __syncthreads();
    if (part == 0) {
        float tot = lds[t] + lds[t + 64] + lds[t + 128] + lds[t + 192];
        if (o < 16384) {
            int k = o >> 7, nn = o & 127;
            kvth[nn * 128 + k] = f2bf(tot);
        } else {
            sums[o - 16384] = tot;
        }
    }
}

__global__ void rdeg_k(const int* __restrict__ cur, float* __restrict__ rdeg, int n)
{
    int i = blockIdx.x * 256 + threadIdx.x;
    if (i < n) {
        int c = cur[i];
        rdeg[i] = (c > 0) ? rsqrtf((float)c) : 0.f;
    }
}

// ------ fused gather + LN + ELU: 4 nodes/wave (16 lanes/node), 8B loads -----
__global__ __launch_bounds__(256) void gather_ln_elu4(
    const int* __restrict__ cnt, const int* __restrict__ crow,
    const float* __restrict__ rdeg,
    const unsigned char* __restrict__ g, const float* __restrict__ accin,
    const float* __restrict__ gam, const float* __restrict__ bet,
    float* __restrict__ outf, unsigned short* __restrict__ out16, int n)
{
    int node = (int)((blockIdx.x * 256 + threadIdx.x) >> 4);
    int li   = threadIdx.x & 15;
    if (node >= n) return;

    int cn = cnt[node]; if (cn > SLOTS) cn = SLOTS;
    const int* cr = &crow[(size_t)node * SLOTS];
    float rd = rdeg[node];
    const unsigned b8 = (unsigned)li * 8u;
    float4 a0 = *(const float4*)&accin[(size_t)node * HID + li * 8];
    float4 a1 = *(const float4*)&accin[(size_t)node * HID + li * 8 + 4];

    auto acc8 = [&](uint2 U_, float W_) {
        f32x2 pa = __builtin_amdgcn_cvt_pk_f32_fp8((int)U_.x, false);
        f32x2 pb = __builtin_amdgcn_cvt_pk_f32_fp8((int)U_.x, true);
        f32x2 pc = __builtin_amdgcn_cvt_pk_f32_fp8((int)U_.y, false);
        f32x2 pd = __builtin_amdgcn_cvt_pk_f32_fp8((int)U_.y, true);
        a0.x += W_ * pa[0]; a0.y += W_ * pa[1];
        a0.z += W_ * pb[0]; a0.w += W_ * pb[1];
        a1.x += W_ * pc[0]; a1.y += W_ * pc[1];
        a1.z += W_ * pd[0]; a1.w += W_ * pd[1];
    };

    int i = 0;
    for (; i + 3 < cn; i += 4) {
        int   r0 = cr[i],     r1 = cr[i + 1];
        int   r2 = cr[i + 2], r3 = cr[i + 3];
        float w0 = rd * rdeg[r0], w1 = rd * rdeg[r1];
        float w2 = rd * rdeg[r2], w3 = rd * rdeg[r3];
        uint2 u0 = *(const uint2*)&g[(unsigned)r0 * 128u + b8];
        uint2 u1 = *(const uint2*)&g[(unsigned)r1 * 128u + b8];
        uint2 u2 = *(const uint2*)&g[(unsigned)r2 * 128u + b8];
        uint2 u3 = *(const uint2*)&g[(unsigned)r3 * 128u + b8];
        acc8(u0, w0); acc8(u1, w1); acc8(u2, w2); acc8(u3, w3);
    }
    for (; i < cn; ++i) {
        int r0 = cr[i];
        float w0 = rd * rdeg[r0];
        uint2 u0 = *(const uint2*)&g[(unsigned)r0 * 128u + b8];
        acc8(u0, w0);
    }

    float sm = a0.x + a0.y + a0.z + a0.w + a1.x + a1.y + a1.z + a1.w;
    float ss = a0.x * a0.x + a0.y * a0.y + a0.z * a0.z + a0.w * a0.w
             + a1.x * a1.x + a1.y * a1.y + a1.z * a1.z + a1.w * a1.w;
    #pragma unroll
    for (int o = 8; o; o >>= 1) { sm += __shfl_xor(sm, o); ss += __shfl_xor(ss, o); }
    float mu  = sm * (1.f / 128.f);
    float var = ss * (1.f / 128.f) - mu * mu;
    float rs  = rsqrtf(var + EPS);
    float4 gm0 = *(const float4*)&gam[li * 8];
    float4 gm1 = *(const float4*)&gam[li * 8 + 4];
    float4 bt0 = *(const float4*)&bet[li * 8];
    float4 bt1 = *(const float4*)&bet[li * 8 + 4];
    float y0 = eluf((a0.x - mu) * rs * gm0.x + bt0.x);
    float y1 = eluf((a0.y - mu) * rs * gm0.y + bt0.y);
    float y2 = eluf((a0.z - mu) * rs * gm0.z + bt0.z);
    float y3 = eluf((a0.w - mu) * rs * gm0.w + bt0.w);
    float y4 = eluf((a1.x - mu) * rs * gm1.x + bt1.x);
    float y5 = eluf((a1.y - mu) * rs * gm1.y + bt1.y);
    float y6 = eluf((a1.z - mu) * rs * gm1.z + bt1.z);
    float y7 = eluf((a1.w - mu) * rs * gm1.w + bt1.w);
    if (out16) {
        us16x4 o0 = (us16x4){f2bf(y0), f2bf(y1), f2bf(y2), f2bf(y3)};
        us16x4 o1 = (us16x4){f2bf(y4), f2bf(y5), f2bf(y6), f2bf(y7)};
        *(us16x4*)&out16[(size_t)node * HID + li * 8]     = o0;
        *(us16x4*)&out16[(size_t)node * HID + li * 8 + 4] = o1;
    } else {
        *(float4*)&outf[(size_t)node * HID + li * 8]     = make_float4(y0, y1, y2, y3);
        *(float4*)&outf[(size_t)node * HID + li * 8 + 4] = make_float4(y4, y5, y6, y7);
    }
}

// ---------------------------------------------------------------------------
extern "C" void kernel_launch(void* const* d_in, const int* in_sizes, int n_in,
                              void* d_out, int out_size, void* d_ws, size_t ws_size,
                              hipStream_t stream)
{
    const float* x      = (const float*)d_in[0];
    const int*   ei     = (const int*)  d_in[1];
    const float* mlp_W0 = (const float*)d_in[2];
    const float* mlp_b0 = (const float*)d_in[3];
    const float* mlp_W  = (const float*)d_in[4];
    const float* mlp_b  = (const float*)d_in[5];
    const float* bn_g   = (const float*)d_in[6];
    const float* bn_b   = (const float*)d_in[7];
    const float* bn_m   = (const float*)d_in[8];
    const float* bn_v   = (const float*)d_in[9];
    const float* Wq = (const float*)d_in[10]; const float* bq = (const float*)d_in[11];
    const float* Wk = (const float*)d_in[12]; const float* bk = (const float*)d_in[13];
    const float* Wv = (const float*)d_in[14]; const float* bv = (const float*)d_in[15];
    const float* Wg = (const float*)d_in[16]; const float* bg = (const float*)d_in[17];
    const float* Wr = (const float*)d_in[18]; const float* br = (const float*)d_in[19];
    const float* ln_g = (const float*)d_in[20];
    const float* ln_b = (const float*)d_in[21];

    const int N = in_sizes[0] / INC;
    const int E = in_sizes[1] / 2;
    const size_t P = (size_t)N * HID;
    const int gemmGrid = (N + 63) / 64;

    // workspace layout
    unsigned short* partial = (unsigned short*)d_ws;            // max(gemmGrid*16640, P) bf16
    size_t partUS = (size_t)gemmGrid * 16640;
    if (partUS < P) partUS = P;
    unsigned short* h16  = partial + partUS;                    // P bf16
    unsigned short* qb16 = h16 + P;                             // P bf16
    unsigned char*  gb8  = (unsigned char*)(qb16 + P);          // P fp8
    float* kvs  = (float*)(gb8 + P);                            // 256 f: [sum_kn][sum_v]
    int*   crow = (int*)(kvs + 256);                            // N*SLOTS
    int*   cnt  = crow + (size_t)N * SLOTS;                     // N
    float* rdeg = (float*)(cnt + N);                            // N
    unsigned short* wt = (unsigned short*)(rdeg + N);

    // MLP scratch (dead before first partial/qb16 use)
    unsigned short* mlpA = partial;
    unsigned short* mlpB = qb16;

    unsigned short* WTh[18];
    int Ks[18];
    size_t woff = 0;
    for (int m = 0; m < 18; ++m) {
        int K = (m == 0) ? INC : HID;
        Ks[m] = K;
        WTh[m] = wt + woff;           woff += (size_t)128 * K;
    }
    unsigned short* kvth = wt + woff; woff += 16384;
    float* acc = (float*)d_out;

    const int gw4Grid  = (N + 15) / 16;
    const int nodeGrid = (N + 255) / 256;

    // CSR chunk bounds: 5 chunks hidden under MLP0/1/2, qkvgr0, num_combine0
    int eb[6];
    for (int i = 0; i <= 5; ++i) eb[i] = (int)(((long long)E * i) / 5);
    auto cb = [&](int i) { return (eb[i + 1] - eb[i] + 255) / 256; };

    // --- weight pre-convert (hi-only, transposed) ---
    WConvArgs wa;
    const float* srcs[18];
    srcs[0] = mlp_W0; srcs[1] = mlp_W; srcs[2] = mlp_W + (size_t)HID * HID;
    for (int l = 0; l < NLAYER; ++l) {
        const size_t wo = (size_t)l * HID * HID;
        srcs[3 + l * 5 + 0] = Wq + wo;
        srcs[3 + l * 5 + 1] = Wk + wo;
        srcs[3 + l * 5 + 2] = Wv + wo;
        srcs[3 + l * 5 + 3] = Wg + wo;
        srcs[3 + l * 5 + 4] = Wr + wo;
    }
    for (int m = 0; m < 18; ++m) {
        wa.src[m] = srcs[m]; wa.dh[m] = WTh[m]; wa.K[m] = Ks[m];
    }
    conv_weights<<<dim3(18, 8), 256, 0, stream>>>(wa);

    hipMemsetAsync(cnt, 0, (size_t)N * sizeof(int), stream);

    // --- MLP (each hosts a CSR chunk) ---
    gemm_mlp<INC, true><<<gemmGrid + cb(0), 256, 0, stream>>>(x, nullptr, WTh[0], mlp_b0,
        bn_g, bn_b, bn_m, bn_v, mlpA, N, ei, cnt, crow, E, eb[0], eb[1], gemmGrid);
    gemm_mlp<HID, false><<<gemmGrid + cb(1), 256, 0, stream>>>(nullptr, mlpA, WTh[1], mlp_b,
        bn_g + HID, bn_b + HID, bn_m + HID, bn_v + HID, mlpB, N,
        ei, cnt, crow, E, eb[1], eb[2], gemmGrid);
    gemm_mlp<HID, false><<<gemmGrid + cb(2), 256, 0, stream>>>(nullptr, mlpB, WTh[2], mlp_b + HID,
        bn_g + 2 * HID, bn_b + 2 * HID, bn_m + 2 * HID, bn_v + 2 * HID, h16, N,
        ei, cnt, crow, E, eb[2], eb[3], gemmGrid);

    // --- TransConv layers ---
    for (int l = 0; l < NLAYER; ++l) {
        const int bo = l * HID;
        const bool l0 = (l == 0);

        QKVGRArgs qa;
        for (int m = 0; m < 5; ++m) qa.wh[m] = WTh[3 + l * 5 + m];
        qa.bias[0] = bq + bo; qa.bias[1] = bk + bo; qa.bias[2] = bv + bo;
        qa.bias[3] = bg + bo; qa.bias[4] = br + bo;

        // h16 -> qn, g, acc(r+res), partial kvs  (layer 0 hosts CSR chunk 3)
        fused_qkvgr<<<gemmGrid + (l0 ? cb(3) : 0), 256, 0, stream>>>(h16, qa,
            qb16, gb8, acc, partial, N,
            ei, cnt, crow, E, l0 ? eb[3] : 0, l0 ? eb[4] : 0, gemmGrid);

        // kvs = sum of per-block partials
        reduce_kvs_p2<<<260, 256, 0, stream>>>(partial, gemmGrid, kvth, kvs);

        // acc += (qn @ kvs + sum_v) / (qn . sum_kn + N)  (layer 0 hosts chunk 4)
        gemm_num_combine<<<gemmGrid + (l0 ? cb(4) : 0), 256, 0, stream>>>(qb16, kvth,
            kvs + 128, kvs, (float)N, acc, N,
            ei, cnt, crow, E, l0 ? eb[4] : 0, l0 ? eb[5] : 0, gemmGrid);

        // rdeg after the last CSR chunk, before the first gather
        if (l0) rdeg_k<<<nodeGrid, 256, 0, stream>>>(cnt, rdeg, N);

        // fused gather (fp8 g, 4 nodes/wave) + LN + ELU
        bool last = (l == NLAYER - 1);
        gather_ln_elu4<<<gw4Grid, 256, 0, stream>>>(cnt, crow, rdeg,
            gb8, acc, ln_g + bo, ln_b + bo,
            last ? acc : nullptr, last ? nullptr : h16, N);
    }
}

// Round 13
// 764.364 us; speedup vs baseline: 1.8398x; 1.3874x over previous
//
#include <hip/hip_runtime.h>
#include <cstdint>
#include <cstddef>

#define HID 128
#define INC 256
#define NLAYER 3
#define SLOTS 96
#define P2G 16            // partial-reduction groups

static constexpr float EPS = 1e-5f;

typedef __attribute__((ext_vector_type(8))) short s16x8;
typedef __attribute__((ext_vector_type(4))) unsigned short us16x4;
typedef __attribute__((ext_vector_type(4))) float f32x4;
typedef __attribute__((ext_vector_type(2))) float f32x2;

__device__ __forceinline__ float eluf(float x) { return x > 0.f ? x : expm1f(x); }

__device__ __forceinline__ unsigned short f2bf(float x)
{
    unsigned u = __float_as_uint(x);
    u += 0x7FFFu + ((u >> 16) & 1u);
    return (unsigned short)(u >> 16);
}

__device__ __forceinline__ float bf2f(unsigned short u)
{
    return __uint_as_float(((unsigned)u) << 16);
}

__device__ __forceinline__ unsigned char f2fp8(float x)
{
    return (unsigned char)(__builtin_amdgcn_cvt_pk_fp8_f32(x, x, 0, false) & 0xFF);
}

// ---- CSR co-run side-job: blocks past hostGrid fill an edge range ----------
__device__ __forceinline__ bool csr_side(int hostGrid, const int* __restrict__ ei,
                                         int* cnt, int* crow, int Etot, int e0, int e1)
{
    if ((int)blockIdx.x < hostGrid) return false;
    int e = e0 + (int)(blockIdx.x - hostGrid) * 256 + (int)threadIdx.x;
    if (e < e1) {
        int r = ei[e], c = ei[Etot + e];
        int p = atomicAdd(&cnt[c], 1);
        if (p < SLOTS) crow[(size_t)c * SLOTS + p] = r;
    }
    return true;
}

// ---------------------------------------------------------------------------
// MLP GEMM, hi-only bf16: C16 = bf16(ELU(BN(A[n,K] @ W + bias))).
// ---------------------------------------------------------------------------
template<int K, bool IN32>
__global__ __launch_bounds__(256) void gemm_mlp(
    const float* __restrict__ Af, const unsigned short* __restrict__ A16,
    const unsigned short* __restrict__ Wth,
    const float* __restrict__ bias,
    const float* __restrict__ bng, const float* __restrict__ bnb,
    const float* __restrict__ bnm, const float* __restrict__ bnv,
    unsigned short* __restrict__ C16, int n,
    const int* __restrict__ ei, int* cntp, int* crowp, int Etot, int e0, int e1,
    int hostGrid)
{
    if (csr_side(hostGrid, ei, cntp, crowp, Etot, e0, e1)) return;

    __shared__ unsigned short Ah[64 * 64], Wh[128 * 64];
    const int t = threadIdx.x;
    const int l = t & 63;
    const int w = t >> 6;
    const int l15 = l & 15;
    const int row0 = blockIdx.x * 64;

    char* cAh = (char*)Ah;
    char* cWh = (char*)Wh;

    f32x4 acc[8] = {};

    for (int kc = 0; kc < K; kc += 64) {
        if (IN32) {
            #pragma unroll
            for (int i = 0; i < 4; ++i) {
                int f = t + 256 * i;
                int r = f >> 4, c4 = f & 15;
                int gr = row0 + r; if (gr > n - 1) gr = n - 1;
                float4 a4 = *(const float4*)&Af[(size_t)gr * K + kc + c4 * 4];
                int byte = r * 128 + (((c4 >> 1) * 16) ^ ((r & 7) << 4)) + (c4 & 1) * 8;
                *(us16x4*)(cAh + byte) =
                    (us16x4){f2bf(a4.x), f2bf(a4.y), f2bf(a4.z), f2bf(a4.w)};
            }
        } else {
            #pragma unroll
            for (int i = 0; i < 2; ++i) {
                int f = t + 256 * i;
                int r = f >> 3, c8 = f & 7;
                int gr = row0 + r; if (gr > n - 1) gr = n - 1;
                int byte = r * 128 + ((c8 * 16) ^ ((r & 7) << 4));
                *(s16x8*)(cAh + byte) = *(const s16x8*)&A16[(size_t)gr * K + kc + c8 * 8];
            }
        }
        #pragma unroll
        for (int i = 0; i < 4; ++i) {
            int f = t + 256 * i;
            int nr = f >> 3, c8 = f & 7;
            size_t gsrc = (size_t)nr * K + kc + c8 * 8;
            int byte = nr * 128 + ((c8 * 16) ^ ((nr & 7) << 4));
            *(s16x8*)(cWh + byte) = *(const s16x8*)&Wth[gsrc];
        }
        __syncthreads();
        #pragma unroll
        for (int ks = 0; ks < 2; ++ks) {
            int jA = ks * 4 + (l >> 4);
            int ar = w * 16 + l15;
            int aoff = ar * 128 + ((jA * 16) ^ ((ar & 7) << 4));
            s16x8 fah = *(s16x8*)(cAh + aoff);
            #pragma unroll
            for (int nt = 0; nt < 8; ++nt) {
                int nr = nt * 16 + l15;
                int boff = nr * 128 + ((jA * 16) ^ ((nr & 7) << 4));
                acc[nt] = __builtin_amdgcn_mfma_f32_16x16x32_bf16(fah, *(s16x8*)(cWh + boff), acc[nt], 0, 0, 0);
            }
        }
        __syncthreads();
    }

    const int rbase = row0 + w * 16 + ((l >> 4) << 2);
    #pragma unroll
    for (int nt = 0; nt < 8; ++nt) {
        int col = nt * 16 + l15;
        float bb = bias[col];
        float gm = bng[col], bt = bnb[col], mn = bnm[col], vr = bnv[col];
        #pragma unroll
        for (int r = 0; r < 4; ++r) {
            int row = rbase + r;
            if (row < n) {
                float o = acc[nt][r] + bb;
                o = eluf((o - mn) * rsqrtf(vr + EPS) * gm + bt);
                C16[(size_t)row * HID + col] = f2bf(o);
            }
        }
    }
}

// ---------------------------------------------------------------------------
// Fused per-layer QKVGR + kvs: hi-only bf16, W single-buffered.
// ---------------------------------------------------------------------------
struct QKVGRArgs {
    const unsigned short* wh[5];
    const float* bias[5];
};

__global__ __launch_bounds__(256) void fused_qkvgr(
    const unsigned short* __restrict__ A16, QKVGRArgs ar,
    unsigned short* __restrict__ qb16,
    unsigned char* __restrict__ gb8, float* __restrict__ accout,
    unsigned short* __restrict__ partial, int n,
    const int* __restrict__ ei, int* cntp, int* crowp, int Etot, int e0, int e1,
    int hostGrid)
{
    if (csr_side(hostGrid, ei, cntp, crowp, Etot, e0, e1)) return;

    __shared__ char smem[65536];
    char* cA  = smem;             // 16KB: staged h; becomes knT after m=1
    char* cW  = smem + 16384;     // 32KB: W (single-buffered)
    char* cVT = smem + 49152;     // 16KB: vT

    const int t = threadIdx.x;
    const int l = t & 63;
    const int w = t >> 6;
    const int l15 = l & 15;
    const int row0 = blockIdx.x * 64;

    #pragma unroll
    for (int i = 0; i < 4; ++i) {
        int f = t + 256 * i;
        int r = f >> 4, c8 = f & 15;
        int gr = row0 + r; if (gr > n - 1) gr = n - 1;
        int byte = r * 256 + ((c8 * 16) ^ ((r & 7) << 4));
        *(s16x8*)(cA + byte) = *(const s16x8*)&A16[(size_t)gr * HID + c8 * 8];
    }
    __syncthreads();

    s16x8 fah[4];
    {
        const int arow = w * 16 + l15;
        #pragma unroll
        for (int ks = 0; ks < 4; ++ks) {
            int aoff = arow * 256 + (((ks * 64) + (l >> 4) * 16) ^ ((arow & 7) << 4));
            fah[ks] = *(s16x8*)(cA + aoff);
        }
    }
    __syncthreads();   // all frags loaded before cA is reused at m=1

    const int rbase = row0 + w * 16 + ((l >> 4) << 2);
    const int rtb   = w * 16 + ((l >> 4) << 2);

    for (int m = 0; m < 5; ++m) {
        {
            const unsigned short* wh = ar.wh[m];
            #pragma unroll
            for (int i = 0; i < 8; ++i) {
                int f = t + 256 * i;
                int nr = f >> 4, c8 = f & 15;
                int byte = nr * 256 + ((c8 * 16) ^ ((nr & 7) << 4));
                *(s16x8*)(cW + byte) = *(const s16x8*)&wh[(size_t)nr * HID + c8 * 8];
            }
        }
        __syncthreads();

        f32x4 acc[8] = {};
        #pragma unroll
        for (int ks = 0; ks < 4; ++ks) {
            #pragma unroll
            for (int nt = 0; nt < 8; ++nt) {
                int nr = nt * 16 + l15;
                int boff = nr * 256 + (((ks * 64) + (l >> 4) * 16) ^ ((nr & 7) << 4));
                acc[nt] = __builtin_amdgcn_mfma_f32_16x16x32_bf16(fah[ks], *(s16x8*)(cW + boff), acc[nt], 0, 0, 0);
            }
        }

        float bb[8];
        #pragma unroll
        for (int nt = 0; nt < 8; ++nt) bb[nt] = ar.bias[m][nt * 16 + l15];

        if (m <= 1) {
            #pragma unroll
            for (int r = 0; r < 4; ++r) {
                float ss = 0.f;
                #pragma unroll
                for (int nt = 0; nt < 8; ++nt) {
                    float o = acc[nt][r] + bb[nt];
                    ss += o * o;
                }
                ss += __shfl_xor(ss, 1); ss += __shfl_xor(ss, 2);
                ss += __shfl_xor(ss, 4); ss += __shfl_xor(ss, 8);
                float rn = rsqrtf(ss);
                int row = rbase + r;
                if (m == 0) {
                    if (row < n) {
                        #pragma unroll
                        for (int nt = 0; nt < 8; ++nt)
                            qb16[(size_t)row * HID + nt * 16 + l15] = f2bf((acc[nt][r] + bb[nt]) * rn);
                    }
                } else {
                    int rt = rtb + r;
                    #pragma unroll
                    for (int nt = 0; nt < 8; ++nt) {
                        int kd = nt * 16 + l15;
                        unsigned short v16 = (row < n) ? f2bf((acc[nt][r] + bb[nt]) * rn) : (unsigned short)0;
                        int byte = kd * 128 + ((2 * rt) ^ ((kd & 7) << 4));
                        *(unsigned short*)(cA + byte) = v16;
                    }
                }
            }
        } else if (m == 2) {
            #pragma unroll
            for (int r = 0; r < 4; ++r) {
                int row = rbase + r;
                int rt = rtb + r;
                #pragma unroll
                for (int nt = 0; nt < 8; ++nt) {
                    int vd = nt * 16 + l15;
                    unsigned short v16 = (row < n) ? f2bf(acc[nt][r] + bb[nt]) : (unsigned short)0;
                    int byte = vd * 128 + ((2 * rt) ^ ((vd & 7) << 4));
                    *(unsigned short*)(cVT + byte) = v16;
                }
            }
        } else if (m == 3) {
            #pragma unroll
            for (int r = 0; r < 4; ++r) {
                int row = rbase + r;
                if (row < n) {
                    #pragma unroll
                    for (int nt = 0; nt < 8; ++nt)
                        gb8[(size_t)row * HID + nt * 16 + l15] = f2fp8(acc[nt][r] + bb[nt]);
                }
            }
        } else {
            #pragma unroll
            for (int r = 0; r < 4; ++r) {
                int row = rbase + r;
                if (row < n) {
                    #pragma unroll
                    for (int nt = 0; nt < 8; ++nt) {
                        int col = nt * 16 + l15;
                        accout[(size_t)row * HID + col] =
                            acc[nt][r] + bb[nt] + bf2f(A16[(size_t)row * HID + col]);
                    }
                }
            }
        }
        __syncthreads();
    }

    // ---- tail: partial kvs[kd][vd] = sum_r knT[kd][r] * vT[vd][r], K=64 ----
    f32x4 kacc[2][8] = {};
    #pragma unroll
    for (int ks = 0; ks < 2; ++ks) {
        #pragma unroll
        for (int mt = 0; mt < 2; ++mt) {
            int kd = w * 32 + mt * 16 + l15;
            int aoff = kd * 128 + ((ks * 64 + (l >> 4) * 16) ^ ((kd & 7) << 4));
            s16x8 fa = *(s16x8*)(cA + aoff);
            #pragma unroll
            for (int nt = 0; nt < 8; ++nt) {
                int vd = nt * 16 + l15;
                int boff = vd * 128 + ((ks * 64 + (l >> 4) * 16) ^ ((vd & 7) << 4));
                kacc[mt][nt] = __builtin_amdgcn_mfma_f32_16x16x32_bf16(fa, *(s16x8*)(cVT + boff), kacc[mt][nt], 0, 0, 0);
            }
        }
    }
    unsigned short* pb = partial + (size_t)blockIdx.x * 16640;
    #pragma unroll
    for (int mt = 0; mt < 2; ++mt) {
        #pragma unroll
        for (int nt = 0; nt < 8; ++nt) {
            #pragma unroll
            for (int r = 0; r < 4; ++r) {
                int kd = w * 32 + mt * 16 + ((l >> 4) << 2) + r;
                pb[kd * 128 + nt * 16 + l15] = f2bf(kacc[mt][nt][r]);
            }
        }
    }
    {
        float s = 0.f;
        if (t < 128) {
            #pragma unroll 8
            for (int r = 0; r < 64; ++r) {
                int byte = t * 128 + ((2 * r) ^ ((t & 7) << 4));
                s += bf2f(*(unsigned short*)(cA + byte));
            }
            pb[16384 + t] = f2bf(s);
        } else {
            int vd = t - 128;
            #pragma unroll 8
            for (int r = 0; r < 64; ++r) {
                int byte = vd * 128 + ((2 * r) ^ ((vd & 7) << 4));
                s += bf2f(*(unsigned short*)(cVT + byte));
            }
            pb[16512 + vd] = f2bf(s);
        }
    }
}

// ---------------------------------------------------------------------------
// num+combine: accio += (qn @ kvs + sum_v) / (qn . sum_kn + nf)
// ---------------------------------------------------------------------------
__global__ __launch_bounds__(256) void gemm_num_combine(
    const unsigned short* __restrict__ A16,
    const unsigned short* __restrict__ Bth,
    const float* __restrict__ sumv, const float* __restrict__ snk,
    float nf, float* __restrict__ accio, int n,
    const int* __restrict__ ei, int* cntp, int* crowp, int Etot, int e0, int e1,
    int hostGrid)
{
    if (csr_side(hostGrid, ei, cntp, crowp, Etot, e0, e1)) return;

    __shared__ char smem[16384 + 32768];
    char* cA = smem;
    char* cW = smem + 16384;

    const int t = threadIdx.x;
    const int l = t & 63;
    const int w = t >> 6;
    const int l15 = l & 15;
    const int row0 = blockIdx.x * 64;

    #pragma unroll
    for (int i = 0; i < 4; ++i) {
        int f = t + 256 * i;
        int r = f >> 4, c8 = f & 15;
        int gr = row0 + r; if (gr > n - 1) gr = n - 1;
        int byte = r * 256 + ((c8 * 16) ^ ((r & 7) << 4));
        *(s16x8*)(cA + byte) = *(const s16x8*)&A16[(size_t)gr * HID + c8 * 8];
    }
    #pragma unroll
    for (int i = 0; i < 8; ++i) {
        int f = t + 256 * i;
        int nr = f >> 4, c8 = f & 15;
        int byte = nr * 256 + ((c8 * 16) ^ ((nr & 7) << 4));
        *(s16x8*)(cW + byte) = *(const s16x8*)&Bth[(size_t)nr * HID + c8 * 8];
    }
    __syncthreads();

    f32x4 acc[8] = {};
    const int arow = w * 16 + l15;
    #pragma unroll
    for (int ks = 0; ks < 4; ++ks) {
        int aoff = arow * 256 + (((ks * 64) + (l >> 4) * 16) ^ ((arow & 7) << 4));
        s16x8 fa = *(s16x8*)(cA + aoff);
        #pragma unroll
        for (int nt = 0; nt < 8; ++nt) {
            int nr = nt * 16 + l15;
            int boff = nr * 256 + (((ks * 64) + (l >> 4) * 16) ^ ((nr & 7) << 4));
            acc[nt] = __builtin_amdgcn_mfma_f32_16x16x32_bf16(fa, *(s16x8*)(cW + boff), acc[nt], 0, 0, 0);
        }
    }

    const int rbase = row0 + w * 16 + ((l >> 4) << 2);
    const int rtb   = w * 16 + ((l >> 4) << 2);
    float bb[8], skn[8];
    #pragma unroll
    for (int nt = 0; nt < 8; ++nt) {
        bb[nt]  = sumv[nt * 16 + l15];
        skn[nt] = snk[nt * 16 + l15];
    }
    #pragma unroll
    for (int r = 0; r < 4; ++r) {
        int row = rbase + r;
        int rt = rtb + r;
        float p = 0.f;
        #pragma unroll
        for (int nt = 0; nt < 8; ++nt) {
            int byte = rt * 256 + ((2 * (nt * 16 + l15)) ^ ((rt & 7) << 4));
            p += bf2f(*(unsigned short*)(cA + byte)) * skn[nt];
        }
        p += __shfl_xor(p, 1); p += __shfl_xor(p, 2);
        p += __shfl_xor(p, 4); p += __shfl_xor(p, 8);
        float dinv = 1.f / (p + nf);
        if (row < n) {
            #pragma unroll
            for (int nt = 0; nt < 8; ++nt) {
                size_t idx = (size_t)row * HID + nt * 16 + l15;
                accio[idx] += (acc[nt][r] + bb[nt]) * dinv;
            }
        }
    }
}

// ------------------- weight pre-convert (+transpose), hi-only ---------------
struct WConvArgs {
    const float* src[18];
    unsigned short* dh[18];
    int K[18];
};

__global__ void conv_weights(WConvArgs a)
{
    int m = blockIdx.x;
    const float* s = a.src[m];
    unsigned short* dh = a.dh[m];
    int K = a.K[m];
    int tot = 128 * K;
    int slice = (tot + gridDim.y - 1) / gridDim.y;
    int i0 = blockIdx.y * slice;
    int i1 = min(tot, i0 + slice);
    for (int idx = i0 + threadIdx.x; idx < i1; idx += 256) {
        int nn = idx / K, k = idx - nn * K;
        dh[idx] = f2bf(s[(size_t)k * 128 + nn]);
    }
}

// ---- kvs reduce stage A: grid (17, P2G); thread owns an output-quad --------
__global__ __launch_bounds__(256) void reduce_kvs_p2a(
    const unsigned short* __restrict__ partial, int nb,
    float* __restrict__ partial2)
{
    const int oq = blockIdx.x * 256 + threadIdx.x;      // output quad 0..4159
    if (oq >= 4160) return;
    const int g   = blockIdx.y;
    const int per = (nb + P2G - 1) / P2G;
    const int b0  = g * per;
    const int b1  = min(nb, b0 + per);

    float s0 = 0.f, s1 = 0.f, s2 = 0.f, s3 = 0.f;
    int b = b0;
    for (; b + 3 < b1; b += 4) {
        us16x4 u0 = *(const us16x4*)&partial[(size_t)(b + 0) * 16640 + oq * 4];
        us16x4 u1 = *(const us16x4*)&partial[(size_t)(b + 1) * 16640 + oq * 4];
        us16x4 u2 = *(const us16x4*)&partial[(size_t)(b + 2) * 16640 + oq * 4];
        us16x4 u3 = *(const us16x4*)&partial[(size_t)(b + 3) * 16640 + oq * 4];
        s0 += bf2f(u0[0]) + bf2f(u1[0]) + bf2f(u2[0]) + bf2f(u3[0]);
        s1 += bf2f(u0[1]) + bf2f(u1[1]) + bf2f(u2[1]) + bf2f(u3[1]);
        s2 += bf2f(u0[2]) + bf2f(u1[2]) + bf2f(u2[2]) + bf2f(u3[2]);
        s3 += bf2f(u0[3]) + bf2f(u1[3]) + bf2f(u2[3]) + bf2f(u3[3]);
    }
    for (; b < b1; ++b) {
        us16x4 u0 = *(const us16x4*)&partial[(size_t)b * 16640 + oq * 4];
        s0 += bf2f(u0[0]); s1 += bf2f(u0[1]); s2 += bf2f(u0[2]); s3 += bf2f(u0[3]);
    }
    *(f32x4*)&partial2[(size_t)g * 16640 + oq * 4] = (f32x4){s0, s1, s2, s3};
}

// ---- kvs reduce stage B: 65 blocks; sum P2G groups -> kvth + sums ----------
__global__ __launch_bounds__(256) void reduce_kvs_p2b(
    const float* __restrict__ partial2,
    unsigned short* __restrict__ kvth, float* __restrict__ sums)
{
    int o = blockIdx.x * 256 + threadIdx.x;
    if (o >= 16640) return;
    float tot = 0.f;
    #pragma unroll
    for (int g = 0; g < P2G; ++g)
        tot += partial2[(size_t)g * 16640 + o];
    if (o < 16384) {
        int k = o >> 7, nn = o & 127;
        kvth[nn * 128 + k] = f2bf(tot);
    } else {
        sums[o - 16384] = tot;
    }
}

__global__ void rdeg_k(const int* __restrict__ cur, float* __restrict__ rdeg, int n)
{
    int i = blockIdx.x * 256 + threadIdx.x;
    if (i < n) {
        int c = cur[i];
        rdeg[i] = (c > 0) ? rsqrtf((float)c) : 0.f;
    }
}

// ------ fused gather + LN + ELU: 4 nodes/wave (16 lanes/node), 8B loads -----
__global__ __launch_bounds__(256) void gather_ln_elu4(
    const int* __restrict__ cnt, const int* __restrict__ crow,
    const float* __restrict__ rdeg,
    const unsigned char* __restrict__ g, const float* __restrict__ accin,
    const float* __restrict__ gam, const float* __restrict__ bet,
    float* __restrict__ outf, unsigned short* __restrict__ out16, int n)
{
    int node = (int)((blockIdx.x * 256 + threadIdx.x) >> 4);
    int li   = threadIdx.x & 15;
    if (node >= n) return;

    int cn = cnt[node]; if (cn > SLOTS) cn = SLOTS;
    const int* cr = &crow[(size_t)node * SLOTS];
    float rd = rdeg[node];
    const unsigned b8 = (unsigned)li * 8u;
    float4 a0 = *(const float4*)&accin[(size_t)node * HID + li * 8];
    float4 a1 = *(const float4*)&accin[(size_t)node * HID + li * 8 + 4];

    auto acc8 = [&](uint2 U_, float W_) {
        f32x2 pa = __builtin_amdgcn_cvt_pk_f32_fp8((int)U_.x, false);
        f32x2 pb = __builtin_amdgcn_cvt_pk_f32_fp8((int)U_.x, true);
        f32x2 pc = __builtin_amdgcn_cvt_pk_f32_fp8((int)U_.y, false);
        f32x2 pd = __builtin_amdgcn_cvt_pk_f32_fp8((int)U_.y, true);
        a0.x += W_ * pa[0]; a0.y += W_ * pa[1];
        a0.z += W_ * pb[0]; a0.w += W_ * pb[1];
        a1.x += W_ * pc[0]; a1.y += W_ * pc[1];
        a1.z += W_ * pd[0]; a1.w += W_ * pd[1];
    };

    int i = 0;
    for (; i + 3 < cn; i += 4) {
        int   r0 = cr[i],     r1 = cr[i + 1];
        int   r2 = cr[i + 2], r3 = cr[i + 3];
        float w0 = rd * rdeg[r0], w1 = rd * rdeg[r1];
        float w2 = rd * rdeg[r2], w3 = rd * rdeg[r3];
        uint2 u0 = *(const uint2*)&g[(unsigned)r0 * 128u + b8];
        uint2 u1 = *(const uint2*)&g[(unsigned)r1 * 128u + b8];
        uint2 u2 = *(const uint2*)&g[(unsigned)r2 * 128u + b8];
        uint2 u3 = *(const uint2*)&g[(unsigned)r3 * 128u + b8];
        acc8(u0, w0); acc8(u1, w1); acc8(u2, w2); acc8(u3, w3);
    }
    for (; i < cn; ++i) {
        int r0 = cr[i];
        float w0 = rd * rdeg[r0];
        uint2 u0 = *(const uint2*)&g[(unsigned)r0 * 128u + b8];
        acc8(u0, w0);
    }

    float sm = a0.x + a0.y + a0.z + a0.w + a1.x + a1.y + a1.z + a1.w;
    float ss = a0.x * a0.x + a0.y * a0.y + a0.z * a0.z + a0.w * a0.w
             + a1.x * a1.x + a1.y * a1.y + a1.z * a1.z + a1.w * a1.w;
    #pragma unroll
    for (int o = 8; o; o >>= 1) { sm += __shfl_xor(sm, o); ss += __shfl_xor(ss, o); }
    float mu  = sm * (1.f / 128.f);
    float var = ss * (1.f / 128.f) - mu * mu;
    float rs  = rsqrtf(var + EPS);
    float4 gm0 = *(const float4*)&gam[li * 8];
    float4 gm1 = *(const float4*)&gam[li * 8 + 4];
    float4 bt0 = *(const float4*)&bet[li * 8];
    float4 bt1 = *(const float4*)&bet[li * 8 + 4];
    float y0 = eluf((a0.x - mu) * rs * gm0.x + bt0.x);
    float y1 = eluf((a0.y - mu) * rs * gm0.y + bt0.y);
    float y2 = eluf((a0.z - mu) * rs * gm0.z + bt0.z);
    float y3 = eluf((a0.w - mu) * rs * gm0.w + bt0.w);
    float y4 = eluf((a1.x - mu) * rs * gm1.x + bt1.x);
    float y5 = eluf((a1.y - mu) * rs * gm1.y + bt1.y);
    float y6 = eluf((a1.z - mu) * rs * gm1.z + bt1.z);
    float y7 = eluf((a1.w - mu) * rs * gm1.w + bt1.w);
    if (out16) {
        us16x4 o0 = (us16x4){f2bf(y0), f2bf(y1), f2bf(y2), f2bf(y3)};
        us16x4 o1 = (us16x4){f2bf(y4), f2bf(y5), f2bf(y6), f2bf(y7)};
        *(us16x4*)&out16[(size_t)node * HID + li * 8]     = o0;
        *(us16x4*)&out16[(size_t)node * HID + li * 8 + 4] = o1;
    } else {
        *(float4*)&outf[(size_t)node * HID + li * 8]     = make_float4(y0, y1, y2, y3);
        *(float4*)&outf[(size_t)node * HID + li * 8 + 4] = make_float4(y4, y5, y6, y7);
    }
}

// ---------------------------------------------------------------------------
extern "C" void kernel_launch(void* const* d_in, const int* in_sizes, int n_in,
                              void* d_out, int out_size, void* d_ws, size_t ws_size,
                              hipStream_t stream)
{
    const float* x      = (const float*)d_in[0];
    const int*   ei     = (const int*)  d_in[1];
    const float* mlp_W0 = (const float*)d_in[2];
    const float* mlp_b0 = (const float*)d_in[3];
    const float* mlp_W  = (const float*)d_in[4];
    const float* mlp_b  = (const float*)d_in[5];
    const float* bn_g   = (const float*)d_in[6];
    const float* bn_b   = (const float*)d_in[7];
    const float* bn_m   = (const float*)d_in[8];
    const float* bn_v   = (const float*)d_in[9];
    const float* Wq = (const float*)d_in[10]; const float* bq = (const float*)d_in[11];
    const float* Wk = (const float*)d_in[12]; const float* bk = (const float*)d_in[13];
    const float* Wv = (const float*)d_in[14]; const float* bv = (const float*)d_in[15];
    const float* Wg = (const float*)d_in[16]; const float* bg = (const float*)d_in[17];
    const float* Wr = (const float*)d_in[18]; const float* br = (const float*)d_in[19];
    const float* ln_g = (const float*)d_in[20];
    const float* ln_b = (const float*)d_in[21];

    const int N = in_sizes[0] / INC;
    const int E = in_sizes[1] / 2;
    const size_t P = (size_t)N * HID;
    const int gemmGrid = (N + 63) / 64;

    // workspace layout
    unsigned short* partial = (unsigned short*)d_ws;            // max(gemmGrid*16640, P) bf16
    size_t partUS = (size_t)gemmGrid * 16640;
    if (partUS < P) partUS = P;
    unsigned short* h16  = partial + partUS;                    // P bf16
    unsigned short* qb16 = h16 + P;                             // P bf16
    unsigned char*  gb8  = (unsigned char*)(qb16 + P);          // P fp8
    float* kvs  = (float*)(gb8 + P);                            // 256 f
    float* partial2 = kvs + 256;                                // P2G*16640 f32
    int*   crow = (int*)(partial2 + (size_t)P2G * 16640);       // N*SLOTS
    int*   cnt  = crow + (size_t)N * SLOTS;                     // N
    float* rdeg = (float*)(cnt + N);                            // N
    unsigned short* wt = (unsigned short*)(rdeg + N);

    // MLP scratch (dead before first partial/qb16 use)
    unsigned short* mlpA = partial;
    unsigned short* mlpB = qb16;

    unsigned short* WTh[18];
    int Ks[18];
    size_t woff = 0;
    for (int m = 0; m < 18; ++m) {
        int K = (m == 0) ? INC : HID;
        Ks[m] = K;
        WTh[m] = wt + woff;           woff += (size_t)128 * K;
    }
    unsigned short* kvth = wt + woff; woff += 16384;
    float* acc = (float*)d_out;

    const int gw4Grid  = (N + 15) / 16;
    const int nodeGrid = (N + 255) / 256;

    // CSR chunk bounds: 5 chunks hidden under MLP0/1/2, qkvgr0, num_combine0
    int eb[6];
    for (int i = 0; i <= 5; ++i) eb[i] = (int)(((long long)E * i) / 5);
    auto cb = [&](int i) { return (eb[i + 1] - eb[i] + 255) / 256; };

    // --- weight pre-convert (hi-only, transposed) ---
    WConvArgs wa;
    const float* srcs[18];
    srcs[0] = mlp_W0; srcs[1] = mlp_W; srcs[2] = mlp_W + (size_t)HID * HID;
    for (int l = 0; l < NLAYER; ++l) {
        const size_t wo = (size_t)l * HID * HID;
        srcs[3 + l * 5 + 0] = Wq + wo;
        srcs[3 + l * 5 + 1] = Wk + wo;
        srcs[3 + l * 5 + 2] = Wv + wo;
        srcs[3 + l * 5 + 3] = Wg + wo;
        srcs[3 + l * 5 + 4] = Wr + wo;
    }
    for (int m = 0; m < 18; ++m) {
        wa.src[m] = srcs[m]; wa.dh[m] = WTh[m]; wa.K[m] = Ks[m];
    }
    conv_weights<<<dim3(18, 8), 256, 0, stream>>>(wa);

    hipMemsetAsync(cnt, 0, (size_t)N * sizeof(int), stream);

    // --- MLP (each hosts a CSR chunk) ---
    gemm_mlp<INC, true><<<gemmGrid + cb(0), 256, 0, stream>>>(x, nullptr, WTh[0], mlp_b0,
        bn_g, bn_b, bn_m, bn_v, mlpA, N, ei, cnt, crow, E, eb[0], eb[1], gemmGrid);
    gemm_mlp<HID, false><<<gemmGrid + cb(1), 256, 0, stream>>>(nullptr, mlpA, WTh[1], mlp_b,
        bn_g + HID, bn_b + HID, bn_m + HID, bn_v + HID, mlpB, N,
        ei, cnt, crow, E, eb[1], eb[2], gemmGrid);
    gemm_mlp<HID, false><<<gemmGrid + cb(2), 256, 0, stream>>>(nullptr, mlpB, WTh[2], mlp_b + HID,
        bn_g + 2 * HID, bn_b + 2 * HID, bn_m + 2 * HID, bn_v + 2 * HID, h16, N,
        ei, cnt, crow, E, eb[2], eb[3], gemmGrid);

    // --- TransConv layers ---
    for (int l = 0; l < NLAYER; ++l) {
        const int bo = l * HID;
        const bool l0 = (l == 0);

        QKVGRArgs qa;
        for (int m = 0; m < 5; ++m) qa.wh[m] = WTh[3 + l * 5 + m];
        qa.bias[0] = bq + bo; qa.bias[1] = bk + bo; qa.bias[2] = bv + bo;
        qa.bias[3] = bg + bo; qa.bias[4] = br + bo;

        // h16 -> qn, g, acc(r+res), partial kvs  (layer 0 hosts CSR chunk 3)
        fused_qkvgr<<<gemmGrid + (l0 ? cb(3) : 0), 256, 0, stream>>>(h16, qa,
            qb16, gb8, acc, partial, N,
            ei, cnt, crow, E, l0 ? eb[3] : 0, l0 ? eb[4] : 0, gemmGrid);

        // kvs = sum of per-block partials (two-stage, parallel)
        reduce_kvs_p2a<<<dim3(17, P2G), 256, 0, stream>>>(partial, gemmGrid, partial2);
        reduce_kvs_p2b<<<65, 256, 0, stream>>>(partial2, kvth, kvs);

        // acc += (qn @ kvs + sum_v) / (qn . sum_kn + N)  (layer 0 hosts chunk 4)
        gemm_num_combine<<<gemmGrid + (l0 ? cb(4) : 0), 256, 0, stream>>>(qb16, kvth,
            kvs + 128, kvs, (float)N, acc, N,
            ei, cnt, crow, E, l0 ? eb[4] : 0, l0 ? eb[5] : 0, gemmGrid);

        // rdeg after the last CSR chunk, before the first gather
        if (l0) rdeg_k<<<nodeGrid, 256, 0, stream>>>(cnt, rdeg, N);

        // fused gather (fp8 g, 4 nodes/wave) + LN + ELU
        bool last = (l == NLAYER - 1);
        gather_ln_elu4<<<gw4Grid, 256, 0, stream>>>(cnt, crow, rdeg,
            gb8, acc, ln_g + bo, ln_b + bo,
            last ? acc : nullptr, last ? nullptr : h16, N);
    }
}